// Round 1
// 2194.066 us; speedup vs baseline: 1.0926x; 1.0926x over previous
//
#include <hip/hip_runtime.h>
#include <cmath>

#define SEQ 2048
#define DIM 512
#define FDIM 512
#define HDIM 2048
#define VOCAB 32000
#define NLAYER 4
#define LNEPS 1e-5f

typedef unsigned short ushort_t;
typedef __attribute__((ext_vector_type(8))) short short8;
typedef __attribute__((ext_vector_type(4))) float f32x4;

// ---------- bf16 helpers (RNE) ----------
__device__ __forceinline__ ushort_t f2bf(float x) {
    union { float f; unsigned int u; } a; a.f = x;
    unsigned int r = a.u + 0x7fffu + ((a.u >> 16) & 1u);
    return (ushort_t)(r >> 16);
}
__device__ __forceinline__ float bf2f(ushort_t b) {
    union { unsigned int u; float f; } a; a.u = ((unsigned int)b) << 16; return a.f;
}

// ---------- async global->LDS 16B ----------
__device__ __forceinline__ void gload_lds16(const ushort_t* g, ushort_t* l) {
    __builtin_amdgcn_global_load_lds(
        (const __attribute__((address_space(1))) void*)g,
        (__attribute__((address_space(3))) void*)l, 16, 0, 0);
}

// =====================================================================
// GEMM: C[M][N](ldc) (+)= scale * A[M][K] @ B[N][K]^T   (bf16 hi/lo x3)
// A,B pre-split compact bf16. 128x128 tile, BK=32, 256 thr (4 waves),
// each wave a 64x64 quadrant = 4x4 tiles of 16x16x32 MFMA, 3 mfma/tile.
// splitk>1: partial-K slices atomicAdd into pre-zeroed C.
// =====================================================================
__global__ __launch_bounds__(256) void gemm_bf16x3_k(
    const ushort_t* __restrict__ Ah, const ushort_t* __restrict__ Al,
    const ushort_t* __restrict__ Bh, const ushort_t* __restrict__ Bl,
    const float* __restrict__ bias, float* __restrict__ C,
    int N, int K, int ldc, float scale, int splitk)
{
    __shared__ ushort_t lds[16384];        // 4 x 8KB: Ah | Al | Bh | Bl
    ushort_t* ldsAh = lds;
    ushort_t* ldsAl = lds + 4096;
    ushort_t* ldsBh = lds + 8192;
    ushort_t* ldsBl = lds + 12288;

    const int tid  = threadIdx.x;
    const int lane = tid & 63, wv = tid >> 6;
    const int wm = wv >> 1, wn = wv & 1;
    const int q = lane >> 4, mlo = lane & 15;
    const int tm = blockIdx.y << 7, tn = blockIdx.x << 7;
    const int ksteps = (K >> 5) / splitk;
    const int kbase  = blockIdx.z * ksteps * 32;

    f32x4 acc[4][4];
#pragma unroll
    for (int i = 0; i < 4; i++)
#pragma unroll
        for (int j = 0; j < 4; j++)
            acc[i][j] = (f32x4){0.f, 0.f, 0.f, 0.f};

    for (int ks = 0; ks < ksteps; ks++) {
        const int k0 = kbase + (ks << 5);
        // ---- stage: 512 16B-chunks per buffer; chunk c=(kb<<7)|i holds
        //      X[i][k0+kb*8 .. +8); lds offset = c*16B. Wave-uniform dst base.
#pragma unroll
        for (int r = 0; r < 2; r++) {
            const int c  = (r << 8) + (wv << 6) + lane;
            const int i  = c & 127, kb = c >> 7;
            const int lofs = ((r << 8) + (wv << 6)) << 3;   // ushort units
            const size_t aoff = (size_t)(tm + i) * K + k0 + (kb << 3);
            const size_t boff = (size_t)(tn + i) * K + k0 + (kb << 3);
            gload_lds16(Ah + aoff, ldsAh + lofs);
            gload_lds16(Al + aoff, ldsAl + lofs);
            gload_lds16(Bh + boff, ldsBh + lofs);
            gload_lds16(Bl + boff, ldsBl + lofs);
        }
        __syncthreads();   // drains vmcnt before any wave reads LDS

        short8 ah[4], al[4], bh[4], bl[4];
#pragma unroll
        for (int t = 0; t < 4; t++) {
            const int ma = ((q << 7) + (wm << 6) + (t << 4) + mlo) << 3;
            const int nb = ((q << 7) + (wn << 6) + (t << 4) + mlo) << 3;
            ah[t] = *(const short8*)&ldsAh[ma];
            al[t] = *(const short8*)&ldsAl[ma];
            bh[t] = *(const short8*)&ldsBh[nb];
            bl[t] = *(const short8*)&ldsBl[nb];
        }
#pragma unroll
        for (int i = 0; i < 4; i++)
#pragma unroll
            for (int j = 0; j < 4; j++) {
                acc[i][j] = __builtin_amdgcn_mfma_f32_16x16x32_bf16(ah[i], bh[j], acc[i][j], 0, 0, 0);
                acc[i][j] = __builtin_amdgcn_mfma_f32_16x16x32_bf16(ah[i], bl[j], acc[i][j], 0, 0, 0);
                acc[i][j] = __builtin_amdgcn_mfma_f32_16x16x32_bf16(al[i], bh[j], acc[i][j], 0, 0, 0);
            }
        __syncthreads();   // all waves done with LDS before next stage
    }

    // ---- epilogue: C/D layout col=lane&15, row=(lane>>4)*4+reg ----
    const bool addb = (bias != nullptr) && (blockIdx.z == 0);
#pragma unroll
    for (int ti = 0; ti < 4; ti++)
#pragma unroll
        for (int tj = 0; tj < 4; tj++) {
            const int col = tn + (wn << 6) + (tj << 4) + mlo;
            const float bb = addb ? bias[col] : 0.f;
#pragma unroll
            for (int r = 0; r < 4; r++) {
                const int row = tm + (wm << 6) + (ti << 4) + (q << 2) + r;
                const float v = acc[ti][tj][r] * scale + bb;
                if (splitk == 1) C[(size_t)row * ldc + col] = v;
                else atomicAdd(&C[(size_t)row * ldc + col], v);
            }
        }
}

// ---------- split fp32[R][C](ld) -> compact bf16 hi/lo [R][C] ----------
__global__ __launch_bounds__(128) void split_k(
    const float* __restrict__ src, int ld, int C,
    ushort_t* __restrict__ dh, ushort_t* __restrict__ dl)
{
    const int row = blockIdx.y;
    const int c4 = ((blockIdx.x << 7) + threadIdx.x) << 2;
    if (c4 >= C) return;
    const float4 v = *(const float4*)&src[(size_t)row * ld + c4];
    ushort_t h[4], l[4];
    const float f[4] = {v.x, v.y, v.z, v.w};
#pragma unroll
    for (int i = 0; i < 4; i++) {
        h[i] = f2bf(f[i]);
        l[i] = f2bf(f[i] - bf2f(h[i]));
    }
    *(ushort4*)&dh[(size_t)row * C + c4] = make_ushort4(h[0], h[1], h[2], h[3]);
    *(ushort4*)&dl[(size_t)row * C + c4] = make_ushort4(l[0], l[1], l[2], l[3]);
}

// ---------- transpose+split fp32[R][C](ld) -> bf16 hi/lo [C][R] ----------
__global__ __launch_bounds__(256) void tsplit_k(
    const float* __restrict__ src, int ld, int R,
    ushort_t* __restrict__ dh, ushort_t* __restrict__ dl)
{
    __shared__ float t[32][33];
    const int c = threadIdx.x & 31, r8 = threadIdx.x >> 5;
    const int bx = blockIdx.x, by = blockIdx.y;
#pragma unroll
    for (int i = 0; i < 4; i++) {
        const int r = (r8 << 2) + i;
        t[r][c] = src[(size_t)((by << 5) + r) * ld + (bx << 5) + c];
    }
    __syncthreads();
#pragma unroll
    for (int i = 0; i < 4; i++) {
        const int rr = (r8 << 2) + i;            // output row' = bx*32+rr
        const float v = t[c][rr];                // src[by*32+c][bx*32+rr]
        const ushort_t h = f2bf(v);
        const ushort_t l = f2bf(v - bf2f(h));
        const size_t o = (size_t)((bx << 5) + rr) * R + (by << 5) + c;
        dh[o] = h; dl[o] = l;
    }
}

// ---------- gather merged qkv bias [1536] ----------
__global__ void gather3_k(const float* a, const float* b, const float* c, float* d)
{
    const int i = blockIdx.x * 256 + threadIdx.x;
    if (i >= 1536) return;
    d[i] = (i < 512) ? a[i] : ((i < 1024) ? b[i - 512] : c[i - 1024]);
}

// ---------- causal softmax over rows of sc[S,S], fused bf16 hi/lo split out ----------
// Single pass: row (<=2048 floats) lives in 2 float4/thread registers.
// Writes the att matrix directly in compact bf16 hi/lo form (= split_k output).
__global__ __launch_bounds__(256) void softmax_causal_split_k(
    const float* __restrict__ sc, ushort_t* __restrict__ dh, ushort_t* __restrict__ dl)
{
    const int i = blockIdx.x;
    const float* row = sc + (size_t)i * SEQ;
    const int tid = threadIdx.x;
    __shared__ float red[4];
    const int base = tid << 2;

    float4 v[2];
    v[0] = *(const float4*)&row[base];
    v[1] = *(const float4*)&row[1024 + base];

    float m = -3.402823466e38f;
#pragma unroll
    for (int c = 0; c < 2; c++) {
        float* f = (float*)&v[c];
        const int idx = (c << 10) + base;
#pragma unroll
        for (int j = 0; j < 4; j++) {
            if (idx + j > i) f[j] = -3.402823466e38f;   // causal mask
            m = fmaxf(m, f[j]);
        }
    }
#pragma unroll
    for (int o = 32; o > 0; o >>= 1) m = fmaxf(m, __shfl_down(m, o, 64));
    if ((tid & 63) == 0) red[tid >> 6] = m;
    __syncthreads();
    m = fmaxf(fmaxf(red[0], red[1]), fmaxf(red[2], red[3]));
    __syncthreads();

    float s = 0.f;
#pragma unroll
    for (int c = 0; c < 2; c++) {
        float* f = (float*)&v[c];
#pragma unroll
        for (int j = 0; j < 4; j++) {
            f[j] = expf(f[j] - m);     // masked lanes: expf(~-3.4e38) == 0
            s += f[j];
        }
    }
#pragma unroll
    for (int o = 32; o > 0; o >>= 1) s += __shfl_down(s, o, 64);
    if ((tid & 63) == 0) red[tid >> 6] = s;
    __syncthreads();
    const float inv = 1.0f / (red[0] + red[1] + red[2] + red[3]);

#pragma unroll
    for (int c = 0; c < 2; c++) {
        float* f = (float*)&v[c];
        const int idx = (c << 10) + base;
        ushort_t hp[4], lp[4];
#pragma unroll
        for (int j = 0; j < 4; j++) {
            const float e = f[j] * inv;         // masked -> exactly 0
            hp[j] = f2bf(e);
            lp[j] = f2bf(e - bf2f(hp[j]));
        }
        *(ushort4*)&dh[(size_t)i * SEQ + idx] = make_ushort4(hp[0], hp[1], hp[2], hp[3]);
        *(ushort4*)&dl[(size_t)i * SEQ + idx] = make_ushort4(lp[0], lp[1], lp[2], lp[3]);
    }
}

// ---------- out = LN(z + res) * g + b  (width 512) ----------
__global__ __launch_bounds__(256) void add_ln_k(
    const float* __restrict__ z, const float* __restrict__ res,
    const float* __restrict__ g, const float* __restrict__ b,
    float* __restrict__ outp)
{
    const int row = blockIdx.x;
    const int tid = threadIdx.x;
    __shared__ float red[4];
    const size_t base = (size_t)row * DIM;
    const float v0 = z[base + tid] + res[base + tid];
    const float v1 = z[base + tid + 256] + res[base + tid + 256];
    float s = v0 + v1;
#pragma unroll
    for (int o = 32; o > 0; o >>= 1) s += __shfl_down(s, o, 64);
    if ((tid & 63) == 0) red[tid >> 6] = s;
    __syncthreads();
    const float mean = (red[0] + red[1] + red[2] + red[3]) * (1.0f / DIM);
    __syncthreads();
    const float d0 = v0 - mean, d1 = v1 - mean;
    float vs = d0 * d0 + d1 * d1;
#pragma unroll
    for (int o = 32; o > 0; o >>= 1) vs += __shfl_down(vs, o, 64);
    if ((tid & 63) == 0) red[tid >> 6] = vs;
    __syncthreads();
    const float var = (red[0] + red[1] + red[2] + red[3]) * (1.0f / DIM);
    const float inv = 1.0f / sqrtf(var + LNEPS);
    outp[base + tid]       = d0 * inv * g[tid] + b[tid];
    outp[base + tid + 256] = d1 * inv * g[tid + 256] + b[tid + 256];
}

// ---------- final row softmax over VOCAB: single-pass, register-resident ----------
// 1024 thr/block, 8 float4/thread (32 VGPR data) -> read row once, write once.
__global__ __launch_bounds__(1024) void softmax_rows_k(float* __restrict__ p)
{
    const int row = blockIdx.x;
    float* r = p + (size_t)row * VOCAB;
    const int tid = threadIdx.x;
    __shared__ float red[16];
    const int base = tid << 2;

    float4 v[8];
#pragma unroll
    for (int c = 0; c < 7; c++) v[c] = *(const float4*)&r[(c << 12) + base];
    const bool tail = (28672 + base) < VOCAB;     // VOCAB%4==0 -> whole-float4 valid
    if (tail) v[7] = *(const float4*)&r[28672 + base];
    else { v[7].x = v[7].y = v[7].z = v[7].w = -3.402823466e38f; }

    float m = -3.402823466e38f;
#pragma unroll
    for (int c = 0; c < 8; c++)
        m = fmaxf(m, fmaxf(fmaxf(v[c].x, v[c].y), fmaxf(v[c].z, v[c].w)));
#pragma unroll
    for (int o = 32; o > 0; o >>= 1) m = fmaxf(m, __shfl_down(m, o, 64));
    if ((tid & 63) == 0) red[tid >> 6] = m;
    __syncthreads();
    m = red[0];
#pragma unroll
    for (int w = 1; w < 16; w++) m = fmaxf(m, red[w]);
    __syncthreads();

    float s = 0.f;
#pragma unroll
    for (int c = 0; c < 8; c++) {
        float* f = (float*)&v[c];
#pragma unroll
        for (int j = 0; j < 4; j++) {
            f[j] = expf(f[j] - m);     // invalid tail: expf(~-3.4e38) == 0
            s += f[j];
        }
    }
#pragma unroll
    for (int o = 32; o > 0; o >>= 1) s += __shfl_down(s, o, 64);
    if ((tid & 63) == 0) red[tid >> 6] = s;
    __syncthreads();
    float tot = 0.f;
#pragma unroll
    for (int w = 0; w < 16; w++) tot += red[w];
    const float inv = 1.0f / tot;

#pragma unroll
    for (int c = 0; c < 7; c++) {
        float4 o4;
        o4.x = v[c].x * inv; o4.y = v[c].y * inv;
        o4.z = v[c].z * inv; o4.w = v[c].w * inv;
        *(float4*)&r[(c << 12) + base] = o4;
    }
    if (tail) {
        float4 o4;
        o4.x = v[7].x * inv; o4.y = v[7].y * inv;
        o4.z = v[7].z * inv; o4.w = v[7].w * inv;
        *(float4*)&r[28672 + base] = o4;
    }
}

extern "C" void kernel_launch(void* const* d_in, const int* in_sizes, int n_in,
                              void* d_out, int out_size, void* d_ws, size_t ws_size,
                              hipStream_t stream)
{
    const float* x   = (const float*)d_in[0];
    const float* Wq  = (const float*)d_in[1];
    const float* bq  = (const float*)d_in[2];
    const float* Wk  = (const float*)d_in[3];
    const float* bk  = (const float*)d_in[4];
    const float* Wv  = (const float*)d_in[5];
    const float* bv  = (const float*)d_in[6];
    const float* Wp  = (const float*)d_in[7];
    const float* bp  = (const float*)d_in[8];
    const float* g1  = (const float*)d_in[9];
    const float* be1 = (const float*)d_in[10];
    const float* W1  = (const float*)d_in[11];
    const float* b1  = (const float*)d_in[12];
    const float* W2  = (const float*)d_in[13];
    const float* b2  = (const float*)d_in[14];
    const float* g2  = (const float*)d_in[15];
    const float* be2 = (const float*)d_in[16];
    const float* Wf  = (const float*)d_in[17];
    const float* bf  = (const float*)d_in[18];
    float* out = (float*)d_out;

    // ---- workspace carve (aligned 256B) ----
    char* ws = (char*)d_ws;
    auto alloc = [&](size_t bytes) {
        void* p = ws;
        ws += (bytes + 255) & ~(size_t)255;
        return p;
    };
    float*    x0   = (float*)alloc((size_t)SEQ * DIM * 4);        // 4 MB
    float*    x1   = (float*)alloc((size_t)SEQ * DIM * 4);        // 4 MB
    float*    qkv  = (float*)alloc((size_t)SEQ * 1536 * 4);       // 12 MB
    float*    zb   = (float*)alloc((size_t)SEQ * FDIM * 4);       // 4 MB
    float*    z2   = (float*)alloc((size_t)SEQ * FDIM * 4);       // 4 MB
    float*    sc   = (float*)alloc((size_t)SEQ * SEQ * 4);        // 16 MB
    ushort_t* Ah   = (ushort_t*)alloc((size_t)SEQ * SEQ * 2);     // 8 MB
    ushort_t* Al   = (ushort_t*)alloc((size_t)SEQ * SEQ * 2);     // 8 MB
    ushort_t* Bh   = (ushort_t*)alloc((size_t)8192 * 512 * 2);    // 8.4 MB
    ushort_t* Bl   = (ushort_t*)alloc((size_t)8192 * 512 * 2);    // 8.4 MB
    float*    bqkv = (float*)alloc(1536 * 4);

    hipMemcpyAsync(x0, x, (size_t)SEQ * DIM * 4, hipMemcpyDeviceToDevice, stream);

    const float att_scale = 1.0f / sqrtf((float)FDIM);
    const dim3 b256(256), b128(128), b1024(1024);

    auto split = [&](const float* src, int ld, int R, int C, ushort_t* dh, ushort_t* dl) {
        split_k<<<dim3((C / 4 + 127) / 128, R), b128, 0, stream>>>(src, ld, C, dh, dl);
    };
    auto tsplit = [&](const float* src, int ld, int R, int C, ushort_t* dh, ushort_t* dl) {
        tsplit_k<<<dim3(C / 32, R / 32), b256, 0, stream>>>(src, ld, R, dh, dl);
    };
    auto gemm = [&](const ushort_t* ah, const ushort_t* al,
                    const ushort_t* bh, const ushort_t* bl,
                    const float* bias, float* C, int N, int K, int ldc,
                    float scale, int splitk) {
        if (splitk > 1)
            hipMemsetAsync(C, 0, (size_t)SEQ * ldc * 4, stream);
        gemm_bf16x3_k<<<dim3(N / 128, SEQ / 128, splitk), b256, 0, stream>>>(
            ah, al, bh, bl, bias, C, N, K, ldc, scale, splitk);
    };

    for (int l = 0; l < NLAYER; l++) {
        const float* Wq_l = Wq + (size_t)l * DIM * FDIM;
        const float* Wk_l = Wk + (size_t)l * DIM * FDIM;
        const float* Wv_l = Wv + (size_t)l * DIM * FDIM;
        const float* Wp_l = Wp + (size_t)l * FDIM * FDIM;
        const float* W1_l = W1 + (size_t)l * FDIM * HDIM;
        const float* W2_l = W2 + (size_t)l * HDIM * DIM;

        // merged qkv: B = [Wq^T; Wk^T; Wv^T]  (1536 x 512)
        tsplit(Wq_l, FDIM, DIM, FDIM, Bh, Bl);
        tsplit(Wk_l, FDIM, DIM, FDIM, Bh + (size_t)512 * 512, Bl + (size_t)512 * 512);
        tsplit(Wv_l, FDIM, DIM, FDIM, Bh + (size_t)1024 * 512, Bl + (size_t)1024 * 512);
        gather3_k<<<dim3(6), b256, 0, stream>>>(bq + l * FDIM, bk + l * FDIM, bv + l * FDIM, bqkv);
        split(x0, DIM, SEQ, DIM, Ah, Al);
        gemm(Ah, Al, Bh, Bl, bqkv, qkv, 1536, DIM, 1536, 1.0f, 2);

        // scores = scale * q @ k^T ; causal softmax fused with bf16 split -> Ah/Al
        split(qkv, 1536, SEQ, FDIM, Ah, Al);                 // q
        split(qkv + 512, 1536, SEQ, FDIM, Bh, Bl);           // k
        gemm(Ah, Al, Bh, Bl, nullptr, sc, SEQ, FDIM, SEQ, att_scale, 2);
        softmax_causal_split_k<<<dim3(SEQ), b256, 0, stream>>>(sc, Ah, Al);

        // z = att @ v   (att already split into Ah/Al by fused softmax)
        tsplit(qkv + 1024, 1536, SEQ, FDIM, Bh, Bl);         // v^T [512][2048]
        gemm(Ah, Al, Bh, Bl, nullptr, zb, FDIM, SEQ, FDIM, 1.0f, 4);

        // z2 = z @ Wp + bp
        split(zb, FDIM, SEQ, FDIM, Ah, Al);
        tsplit(Wp_l, FDIM, FDIM, FDIM, Bh, Bl);
        gemm(Ah, Al, Bh, Bl, bp + l * FDIM, z2, FDIM, FDIM, FDIM, 1.0f, 4);

        // x1 = LN(z2 + x0)
        add_ln_k<<<dim3(SEQ), b256, 0, stream>>>(z2, x0, g1 + l * FDIM, be1 + l * FDIM, x1);

        // h = x1 @ W1 + b1  (into sc)
        split(x1, FDIM, SEQ, FDIM, Ah, Al);
        tsplit(W1_l, HDIM, FDIM, HDIM, Bh, Bl);              // [2048][512]
        gemm(Ah, Al, Bh, Bl, b1 + l * HDIM, sc, HDIM, FDIM, HDIM, 1.0f, 2);

        // h2 = h @ W2 + b2
        split(sc, HDIM, SEQ, HDIM, Ah, Al);
        tsplit(W2_l, DIM, HDIM, DIM, Bh, Bl);                // [512][2048]
        gemm(Ah, Al, Bh, Bl, b2 + l * DIM, z2, DIM, HDIM, DIM, 1.0f, 4);

        // x0 = LN(h2 + x1)
        add_ln_k<<<dim3(SEQ), b256, 0, stream>>>(z2, x1, g2 + l * DIM, be2 + l * DIM, x0);
    }

    // logits = x0 @ Wf + bf, chunked over vocab columns; then row softmax
    split(x0, DIM, SEQ, DIM, Ah, Al);
    for (int n0 = 0; n0 < VOCAB; n0 += 8192) {
        const int nc = (VOCAB - n0 < 8192) ? (VOCAB - n0) : 8192;   // 8192/7424
        tsplit(Wf + n0, VOCAB, DIM, nc, Bh, Bl);                    // [nc][512]
        gemm_bf16x3_k<<<dim3(nc / 128, SEQ / 128, 1), b256, 0, stream>>>(
            Ah, Al, Bh, Bl, bf + n0, out + n0, nc, DIM, VOCAB, 1.0f, 1);
    }
    softmax_rows_k<<<dim3(SEQ), b1024, 0, stream>>>(out);
}

// Round 2
// 1901.548 us; speedup vs baseline: 1.2607x; 1.1538x over previous
//
#include <hip/hip_runtime.h>
#include <cmath>

#define SEQ 2048
#define DIM 512
#define FDIM 512
#define HDIM 2048
#define VOCAB 32000
#define NLAYER 4
#define LNEPS 1e-5f

typedef unsigned short ushort_t;
typedef __attribute__((ext_vector_type(8))) short short8;
typedef __attribute__((ext_vector_type(4))) float f32x4;

// ---------- bf16 helpers (RNE) ----------
__device__ __forceinline__ ushort_t f2bf(float x) {
    union { float f; unsigned int u; } a; a.f = x;
    unsigned int r = a.u + 0x7fffu + ((a.u >> 16) & 1u);
    return (ushort_t)(r >> 16);
}
__device__ __forceinline__ float bf2f(ushort_t b) {
    union { unsigned int u; float f; } a; a.u = ((unsigned int)b) << 16; return a.f;
}

// ---------- async global->LDS 16B ----------
__device__ __forceinline__ void gload_lds16(const ushort_t* g, ushort_t* l) {
    __builtin_amdgcn_global_load_lds(
        (const __attribute__((address_space(1))) void*)g,
        (__attribute__((address_space(3))) void*)l, 16, 0, 0);
}

// =====================================================================
// Shared GEMM core: stages A[M][K](lda),B[N][K](ldb) hi/lo tiles and
// accumulates 3x MFMA (hh, hl, lh). 128x128 tile, BK=32, 4 waves.
// =====================================================================
#define GEMM_CORE(AH, AL, BH, BL, LDA, LDB, KSTEPS, KBASE)                         \
    __shared__ ushort_t lds[16384];                                                \
    ushort_t* ldsAh = lds;                                                         \
    ushort_t* ldsAl = lds + 4096;                                                  \
    ushort_t* ldsBh = lds + 8192;                                                  \
    ushort_t* ldsBl = lds + 12288;                                                 \
    const int tid  = threadIdx.x;                                                  \
    const int lane = tid & 63, wv = tid >> 6;                                      \
    const int wm = wv >> 1, wn = wv & 1;                                           \
    const int q = lane >> 4, mlo = lane & 15;                                      \
    const int tm = blockIdx.y << 7, tn = blockIdx.x << 7;                          \
    f32x4 acc[4][4];                                                               \
    _Pragma("unroll")                                                              \
    for (int i = 0; i < 4; i++)                                                    \
        _Pragma("unroll")                                                          \
        for (int j = 0; j < 4; j++)                                                \
            acc[i][j] = (f32x4){0.f, 0.f, 0.f, 0.f};                               \
    for (int ks = 0; ks < (KSTEPS); ks++) {                                        \
        const int k0 = (KBASE) + (ks << 5);                                        \
        _Pragma("unroll")                                                          \
        for (int r = 0; r < 2; r++) {                                              \
            const int c  = (r << 8) + (wv << 6) + lane;                            \
            const int i  = c & 127, kb = c >> 7;                                   \
            const int lofs = ((r << 8) + (wv << 6)) << 3;                          \
            const size_t aoff = (size_t)(tm + i) * (LDA) + k0 + (kb << 3);         \
            const size_t boff = (size_t)(tn + i) * (LDB) + k0 + (kb << 3);         \
            gload_lds16((AH) + aoff, ldsAh + lofs);                                \
            gload_lds16((AL) + aoff, ldsAl + lofs);                                \
            gload_lds16((BH) + boff, ldsBh + lofs);                                \
            gload_lds16((BL) + boff, ldsBl + lofs);                                \
        }                                                                          \
        __syncthreads();                                                           \
        short8 ah[4], al[4], bh[4], bl[4];                                         \
        _Pragma("unroll")                                                          \
        for (int t = 0; t < 4; t++) {                                              \
            const int ma = ((q << 7) + (wm << 6) + (t << 4) + mlo) << 3;           \
            const int nb = ((q << 7) + (wn << 6) + (t << 4) + mlo) << 3;           \
            ah[t] = *(const short8*)&ldsAh[ma];                                    \
            al[t] = *(const short8*)&ldsAl[ma];                                    \
            bh[t] = *(const short8*)&ldsBh[nb];                                    \
            bl[t] = *(const short8*)&ldsBl[nb];                                    \
        }                                                                          \
        _Pragma("unroll")                                                          \
        for (int i = 0; i < 4; i++)                                                \
            _Pragma("unroll")                                                      \
            for (int j = 0; j < 4; j++) {                                          \
                acc[i][j] = __builtin_amdgcn_mfma_f32_16x16x32_bf16(ah[i], bh[j], acc[i][j], 0, 0, 0); \
                acc[i][j] = __builtin_amdgcn_mfma_f32_16x16x32_bf16(ah[i], bl[j], acc[i][j], 0, 0, 0); \
                acc[i][j] = __builtin_amdgcn_mfma_f32_16x16x32_bf16(al[i], bh[j], acc[i][j], 0, 0, 0); \
            }                                                                      \
        __syncthreads();                                                           \
    }

// ---- fp32-output GEMM, splitk>1 via atomicAdd into pre-zeroed C ----
__global__ __launch_bounds__(256) void gemm_bf16x3_k(
    const ushort_t* __restrict__ Ah, const ushort_t* __restrict__ Al,
    const ushort_t* __restrict__ Bh, const ushort_t* __restrict__ Bl,
    const float* __restrict__ bias, float* __restrict__ C,
    int K, int lda, int ldb, int ldc, float scale, int splitk)
{
    const int ksteps = (K >> 5) / splitk;
    const int kbase  = blockIdx.z * ksteps * 32;
    GEMM_CORE(Ah, Al, Bh, Bl, lda, ldb, ksteps, kbase)
    const bool addb = (bias != nullptr) && (blockIdx.z == 0);
#pragma unroll
    for (int ti = 0; ti < 4; ti++)
#pragma unroll
        for (int tj = 0; tj < 4; tj++) {
            const int col = tn + (wn << 6) + (tj << 4) + mlo;
            const float bb = addb ? bias[col] : 0.f;
#pragma unroll
            for (int r = 0; r < 4; r++) {
                const int row = tm + (wm << 6) + (ti << 4) + (q << 2) + r;
                const float v = acc[ti][tj][r] * scale + bb;
                if (splitk == 1) C[(size_t)row * ldc + col] = v;
                else atomicAdd(&C[(size_t)row * ldc + col], v);
            }
        }
}

// ---- split-output GEMM (splitk==1): epilogue writes bf16 hi/lo directly ----
__global__ __launch_bounds__(256) void gemm_bf16x3_sp_k(
    const ushort_t* __restrict__ Ah, const ushort_t* __restrict__ Al,
    const ushort_t* __restrict__ Bh, const ushort_t* __restrict__ Bl,
    const float* __restrict__ bias,
    ushort_t* __restrict__ Dh, ushort_t* __restrict__ Dl,
    int K, int lda, int ldb, int ldo)
{
    GEMM_CORE(Ah, Al, Bh, Bl, lda, ldb, (K >> 5), 0)
#pragma unroll
    for (int ti = 0; ti < 4; ti++)
#pragma unroll
        for (int tj = 0; tj < 4; tj++) {
            const int col = tn + (wn << 6) + (tj << 4) + mlo;
            const float bb = (bias != nullptr) ? bias[col] : 0.f;
#pragma unroll
            for (int r = 0; r < 4; r++) {
                const int row = tm + (wm << 6) + (ti << 4) + (q << 2) + r;
                const float v = acc[ti][tj][r] + bb;
                const ushort_t h = f2bf(v);
                Dh[(size_t)row * ldo + col] = h;
                Dl[(size_t)row * ldo + col] = f2bf(v - bf2f(h));
            }
        }
}

// ---------- split fp32[R][C](ld) -> compact bf16 hi/lo [R][C] ----------
__global__ __launch_bounds__(128) void split_k(
    const float* __restrict__ src, int ld, int C,
    ushort_t* __restrict__ dh, ushort_t* __restrict__ dl)
{
    const int row = blockIdx.y;
    const int c4 = ((blockIdx.x << 7) + threadIdx.x) << 2;
    if (c4 >= C) return;
    const float4 v = *(const float4*)&src[(size_t)row * ld + c4];
    ushort_t h[4], l[4];
    const float f[4] = {v.x, v.y, v.z, v.w};
#pragma unroll
    for (int i = 0; i < 4; i++) {
        h[i] = f2bf(f[i]);
        l[i] = f2bf(f[i] - bf2f(h[i]));
    }
    *(ushort4*)&dh[(size_t)row * C + c4] = make_ushort4(h[0], h[1], h[2], h[3]);
    *(ushort4*)&dl[(size_t)row * C + c4] = make_ushort4(l[0], l[1], l[2], l[3]);
}

// ---------- transpose+split fp32[R][C](ld) -> bf16 hi/lo [C][R] ----------
__global__ __launch_bounds__(256) void tsplit_k(
    const float* __restrict__ src, int ld, int R,
    ushort_t* __restrict__ dh, ushort_t* __restrict__ dl)
{
    __shared__ float t[32][33];
    const int c = threadIdx.x & 31, r8 = threadIdx.x >> 5;
    const int bx = blockIdx.x, by = blockIdx.y;
#pragma unroll
    for (int i = 0; i < 4; i++) {
        const int r = (r8 << 2) + i;
        t[r][c] = src[(size_t)((by << 5) + r) * ld + (bx << 5) + c];
    }
    __syncthreads();
#pragma unroll
    for (int i = 0; i < 4; i++) {
        const int rr = (r8 << 2) + i;            // output row' = bx*32+rr
        const float v = t[c][rr];                // src[by*32+c][bx*32+rr]
        const ushort_t h = f2bf(v);
        const ushort_t l = f2bf(v - bf2f(h));
        const size_t o = (size_t)((bx << 5) + rr) * R + (by << 5) + c;
        dh[o] = h; dl[o] = l;
    }
}

// ---------- gather merged qkv bias [1536] ----------
__global__ void gather3_k(const float* a, const float* b, const float* c, float* d)
{
    const int i = blockIdx.x * 256 + threadIdx.x;
    if (i >= 1536) return;
    d[i] = (i < 512) ? a[i] : ((i < 1024) ? b[i - 512] : c[i - 1024]);
}

// ---------- bvec = b1 @ W2 + b2 (bvec pre-initialized to b2) ----------
// grid (DIM/128, HDIM/128), 256 thr: each block does 128 cols x 128 h.
__global__ __launch_bounds__(256) void bvec_k(
    const float* __restrict__ b1, const float* __restrict__ W2,
    float* __restrict__ bv)
{
    const int c  = (blockIdx.x << 7) + (threadIdx.x & 127);
    const int h0 = (blockIdx.y << 7) + (threadIdx.x >> 7);
    float acc = 0.f;
#pragma unroll 8
    for (int i = 0; i < 64; i++) {
        const int h = h0 + (i << 1);
        acc += b1[h] * W2[(size_t)h * DIM + c];
    }
    atomicAdd(&bv[c], acc);
}

// ---------- causal softmax over rows of sc[S,S], fused bf16 hi/lo split out ----------
__global__ __launch_bounds__(256) void softmax_causal_split_k(
    const float* __restrict__ sc, ushort_t* __restrict__ dh, ushort_t* __restrict__ dl)
{
    const int i = blockIdx.x;
    const float* row = sc + (size_t)i * SEQ;
    const int tid = threadIdx.x;
    __shared__ float red[4];
    const int base = tid << 2;

    float4 v[2];
    v[0] = *(const float4*)&row[base];
    v[1] = *(const float4*)&row[1024 + base];

    float m = -3.402823466e38f;
#pragma unroll
    for (int c = 0; c < 2; c++) {
        float* f = (float*)&v[c];
        const int idx = (c << 10) + base;
#pragma unroll
        for (int j = 0; j < 4; j++) {
            if (idx + j > i) f[j] = -3.402823466e38f;   // causal mask
            m = fmaxf(m, f[j]);
        }
    }
#pragma unroll
    for (int o = 32; o > 0; o >>= 1) m = fmaxf(m, __shfl_down(m, o, 64));
    if ((tid & 63) == 0) red[tid >> 6] = m;
    __syncthreads();
    m = fmaxf(fmaxf(red[0], red[1]), fmaxf(red[2], red[3]));
    __syncthreads();

    float s = 0.f;
#pragma unroll
    for (int c = 0; c < 2; c++) {
        float* f = (float*)&v[c];
#pragma unroll
        for (int j = 0; j < 4; j++) {
            f[j] = expf(f[j] - m);     // masked lanes: expf(~-3.4e38) == 0
            s += f[j];
        }
    }
#pragma unroll
    for (int o = 32; o > 0; o >>= 1) s += __shfl_down(s, o, 64);
    if ((tid & 63) == 0) red[tid >> 6] = s;
    __syncthreads();
    const float inv = 1.0f / (red[0] + red[1] + red[2] + red[3]);

#pragma unroll
    for (int c = 0; c < 2; c++) {
        float* f = (float*)&v[c];
        const int idx = (c << 10) + base;
        ushort_t hp[4], lp[4];
#pragma unroll
        for (int j = 0; j < 4; j++) {
            const float e = f[j] * inv;         // masked -> exactly 0
            hp[j] = f2bf(e);
            lp[j] = f2bf(e - bf2f(hp[j]));
        }
        *(ushort4*)&dh[(size_t)i * SEQ + idx] = make_ushort4(hp[0], hp[1], hp[2], hp[3]);
        *(ushort4*)&dl[(size_t)i * SEQ + idx] = make_ushort4(lp[0], lp[1], lp[2], lp[3]);
    }
}

// ---------- out = LN(z + res) * g + b, fused bf16 hi/lo split out (width 512) ----------
__global__ __launch_bounds__(256) void add_ln_split_k(
    const float* __restrict__ z, const float* __restrict__ res,
    const float* __restrict__ g, const float* __restrict__ b,
    float* __restrict__ outp, ushort_t* __restrict__ dh, ushort_t* __restrict__ dl)
{
    const int row = blockIdx.x;
    const int tid = threadIdx.x;
    __shared__ float red[4];
    const size_t base = (size_t)row * DIM;
    const float v0 = z[base + tid] + res[base + tid];
    const float v1 = z[base + tid + 256] + res[base + tid + 256];
    float s = v0 + v1;
#pragma unroll
    for (int o = 32; o > 0; o >>= 1) s += __shfl_down(s, o, 64);
    if ((tid & 63) == 0) red[tid >> 6] = s;
    __syncthreads();
    const float mean = (red[0] + red[1] + red[2] + red[3]) * (1.0f / DIM);
    __syncthreads();
    const float d0 = v0 - mean, d1 = v1 - mean;
    float vs = d0 * d0 + d1 * d1;
#pragma unroll
    for (int o = 32; o > 0; o >>= 1) vs += __shfl_down(vs, o, 64);
    if ((tid & 63) == 0) red[tid >> 6] = vs;
    __syncthreads();
    const float var = (red[0] + red[1] + red[2] + red[3]) * (1.0f / DIM);
    const float inv = 1.0f / sqrtf(var + LNEPS);
    const float o0 = d0 * inv * g[tid] + b[tid];
    const float o1 = d1 * inv * g[tid + 256] + b[tid + 256];
    outp[base + tid]       = o0;
    outp[base + tid + 256] = o1;
    const ushort_t h0 = f2bf(o0), h1 = f2bf(o1);
    dh[base + tid]       = h0;  dl[base + tid]       = f2bf(o0 - bf2f(h0));
    dh[base + tid + 256] = h1;  dl[base + tid + 256] = f2bf(o1 - bf2f(h1));
}

// ---------- final row softmax over VOCAB: single-pass, register-resident ----------
__global__ __launch_bounds__(1024) void softmax_rows_k(float* __restrict__ p)
{
    const int row = blockIdx.x;
    float* r = p + (size_t)row * VOCAB;
    const int tid = threadIdx.x;
    __shared__ float red[16];
    const int base = tid << 2;

    float4 v[8];
#pragma unroll
    for (int c = 0; c < 7; c++) v[c] = *(const float4*)&r[(c << 12) + base];
    const bool tail = (28672 + base) < VOCAB;
    if (tail) v[7] = *(const float4*)&r[28672 + base];
    else { v[7].x = v[7].y = v[7].z = v[7].w = -3.402823466e38f; }

    float m = -3.402823466e38f;
#pragma unroll
    for (int c = 0; c < 8; c++)
        m = fmaxf(m, fmaxf(fmaxf(v[c].x, v[c].y), fmaxf(v[c].z, v[c].w)));
#pragma unroll
    for (int o = 32; o > 0; o >>= 1) m = fmaxf(m, __shfl_down(m, o, 64));
    if ((tid & 63) == 0) red[tid >> 6] = m;
    __syncthreads();
    m = red[0];
#pragma unroll
    for (int w = 1; w < 16; w++) m = fmaxf(m, red[w]);
    __syncthreads();

    float s = 0.f;
#pragma unroll
    for (int c = 0; c < 8; c++) {
        float* f = (float*)&v[c];
#pragma unroll
        for (int j = 0; j < 4; j++) {
            f[j] = expf(f[j] - m);
            s += f[j];
        }
    }
#pragma unroll
    for (int o = 32; o > 0; o >>= 1) s += __shfl_down(s, o, 64);
    if ((tid & 63) == 0) red[tid >> 6] = s;
    __syncthreads();
    float tot = 0.f;
#pragma unroll
    for (int w = 0; w < 16; w++) tot += red[w];
    const float inv = 1.0f / tot;

#pragma unroll
    for (int c = 0; c < 7; c++) {
        float4 o4;
        o4.x = v[c].x * inv; o4.y = v[c].y * inv;
        o4.z = v[c].z * inv; o4.w = v[c].w * inv;
        *(float4*)&r[(c << 12) + base] = o4;
    }
    if (tail) {
        float4 o4;
        o4.x = v[7].x * inv; o4.y = v[7].y * inv;
        o4.z = v[7].z * inv; o4.w = v[7].w * inv;
        *(float4*)&r[28672 + base] = o4;
    }
}

extern "C" void kernel_launch(void* const* d_in, const int* in_sizes, int n_in,
                              void* d_out, int out_size, void* d_ws, size_t ws_size,
                              hipStream_t stream)
{
    const float* x   = (const float*)d_in[0];
    const float* Wq  = (const float*)d_in[1];
    const float* bq  = (const float*)d_in[2];
    const float* Wk  = (const float*)d_in[3];
    const float* bk  = (const float*)d_in[4];
    const float* Wv  = (const float*)d_in[5];
    const float* bv  = (const float*)d_in[6];
    const float* Wp  = (const float*)d_in[7];
    const float* bp  = (const float*)d_in[8];
    const float* g1  = (const float*)d_in[9];
    const float* be1 = (const float*)d_in[10];
    const float* W1  = (const float*)d_in[11];
    const float* b1  = (const float*)d_in[12];
    const float* W2  = (const float*)d_in[13];
    const float* b2  = (const float*)d_in[14];
    const float* g2  = (const float*)d_in[15];
    const float* be2 = (const float*)d_in[16];
    const float* Wf  = (const float*)d_in[17];
    const float* bf  = (const float*)d_in[18];
    float* out = (float*)d_out;

    // ---- workspace carve (aligned 256B) ----
    char* ws = (char*)d_ws;
    auto alloc = [&](size_t bytes) {
        void* p = ws;
        ws += (bytes + 255) & ~(size_t)255;
        return p;
    };
    float*    x0   = (float*)alloc((size_t)SEQ * DIM * 4);          // residual stream
    float*    x1   = (float*)alloc((size_t)SEQ * DIM * 4);
    float*    vp   = (float*)alloc((size_t)SEQ * FDIM * 4);         // v @ Wp
    float*    z2   = (float*)alloc((size_t)SEQ * FDIM * 4);
    float*    sc   = (float*)alloc((size_t)SEQ * SEQ * 4);          // scores
    float*    Pt   = (float*)alloc((size_t)FDIM * DIM * 4);         // (W1@W2)^T
    ushort_t* QKVh = (ushort_t*)alloc((size_t)SEQ * 1536 * 2);
    ushort_t* QKVl = (ushort_t*)alloc((size_t)SEQ * 1536 * 2);
    ushort_t* X0h  = (ushort_t*)alloc((size_t)SEQ * DIM * 2);
    ushort_t* X0l  = (ushort_t*)alloc((size_t)SEQ * DIM * 2);
    ushort_t* X1h  = (ushort_t*)alloc((size_t)SEQ * DIM * 2);
    ushort_t* X1l  = (ushort_t*)alloc((size_t)SEQ * DIM * 2);
    ushort_t* AttH = (ushort_t*)alloc((size_t)SEQ * SEQ * 2);
    ushort_t* AttL = (ushort_t*)alloc((size_t)SEQ * SEQ * 2);
    ushort_t* Wth  = (ushort_t*)alloc((size_t)8192 * 512 * 2);      // weight tsplit buf
    ushort_t* Wtl  = (ushort_t*)alloc((size_t)8192 * 512 * 2);
    ushort_t* W1h  = (ushort_t*)alloc((size_t)FDIM * HDIM * 2);
    ushort_t* W1l  = (ushort_t*)alloc((size_t)FDIM * HDIM * 2);
    ushort_t* VpTh = (ushort_t*)alloc((size_t)FDIM * SEQ * 2);
    ushort_t* VpTl = (ushort_t*)alloc((size_t)FDIM * SEQ * 2);
    ushort_t* Pth  = (ushort_t*)alloc((size_t)DIM * FDIM * 2);
    ushort_t* Ptl  = (ushort_t*)alloc((size_t)DIM * FDIM * 2);
    float*    bqkv = (float*)alloc(1536 * 4);
    float*    bvec = (float*)alloc(DIM * 4);

    hipMemcpyAsync(x0, x, (size_t)SEQ * DIM * 4, hipMemcpyDeviceToDevice, stream);

    const float att_scale = 1.0f / sqrtf((float)FDIM);
    const dim3 b256(256), b128(128), b1024(1024);

    auto split = [&](const float* src, int ld, int R, int C, ushort_t* dh, ushort_t* dl) {
        split_k<<<dim3((C / 4 + 127) / 128, R), b128, 0, stream>>>(src, ld, C, dh, dl);
    };
    auto tsplit = [&](const float* src, int ld, int R, int C, ushort_t* dh, ushort_t* dl) {
        tsplit_k<<<dim3(C / 32, R / 32), b256, 0, stream>>>(src, ld, R, dh, dl);
    };
    // fp32-out GEMM, M x N, strided operands
    auto gemm = [&](const ushort_t* ah, const ushort_t* al,
                    const ushort_t* bh, const ushort_t* bl,
                    const float* bias, float* C, int M, int N, int K,
                    int lda, int ldb, int ldc, float scale, int splitk) {
        if (splitk > 1)
            hipMemsetAsync(C, 0, (size_t)M * ldc * 4, stream);
        gemm_bf16x3_k<<<dim3(N / 128, M / 128, splitk), b256, 0, stream>>>(
            ah, al, bh, bl, bias, C, K, lda, ldb, ldc, scale, splitk);
    };
    // split-out GEMM (splitk==1)
    auto gemm_sp = [&](const ushort_t* ah, const ushort_t* al,
                       const ushort_t* bh, const ushort_t* bl,
                       const float* bias, ushort_t* dh, ushort_t* dl,
                       int M, int N, int K, int lda, int ldb, int ldo) {
        gemm_bf16x3_sp_k<<<dim3(N / 128, M / 128), b256, 0, stream>>>(
            ah, al, bh, bl, bias, dh, dl, K, lda, ldb, ldo);
    };

    // initial split of x
    split(x0, DIM, SEQ, DIM, X0h, X0l);

    for (int l = 0; l < NLAYER; l++) {
        const float* Wq_l = Wq + (size_t)l * DIM * FDIM;
        const float* Wk_l = Wk + (size_t)l * DIM * FDIM;
        const float* Wv_l = Wv + (size_t)l * DIM * FDIM;
        const float* Wp_l = Wp + (size_t)l * FDIM * FDIM;
        const float* W1_l = W1 + (size_t)l * FDIM * HDIM;
        const float* W2_l = W2 + (size_t)l * HDIM * DIM;

        // ---- QKV: B = [Wq^T; Wk^T; Wv^T] (1536 x 512); split-out epilogue ----
        tsplit(Wq_l, FDIM, DIM, FDIM, Wth, Wtl);
        tsplit(Wk_l, FDIM, DIM, FDIM, Wth + (size_t)512 * 512, Wtl + (size_t)512 * 512);
        tsplit(Wv_l, FDIM, DIM, FDIM, Wth + (size_t)1024 * 512, Wtl + (size_t)1024 * 512);
        gather3_k<<<dim3(6), b256, 0, stream>>>(bq + l * FDIM, bk + l * FDIM, bv + l * FDIM, bqkv);
        gemm_sp(X0h, X0l, Wth, Wtl, bqkv, QKVh, QKVl, SEQ, 1536, DIM, DIM, DIM, 1536);

        // ---- Vp = v @ Wp (bias deferred to z2 epilogue) ----
        tsplit(Wp_l, FDIM, FDIM, FDIM, Wth, Wtl);
        gemm(QKVh + 1024, QKVl + 1024, Wth, Wtl, nullptr, vp,
             SEQ, FDIM, FDIM, 1536, FDIM, FDIM, 1.0f, 4);

        // ---- scores = scale * q @ k^T ; causal softmax fused split -> AttH/AttL ----
        gemm(QKVh, QKVl, QKVh + 512, QKVl + 512, nullptr, sc,
             SEQ, SEQ, FDIM, 1536, 1536, SEQ, att_scale, 2);
        softmax_causal_split_k<<<dim3(SEQ), b256, 0, stream>>>(sc, AttH, AttL);

        // ---- z2 = att @ Vp + bp ----
        tsplit(vp, FDIM, SEQ, FDIM, VpTh, VpTl);             // [512][2048]
        gemm(AttH, AttL, VpTh, VpTl, bp + l * FDIM, z2,
             SEQ, FDIM, SEQ, SEQ, SEQ, FDIM, 1.0f, 4);

        // ---- x1 = LN(z2 + x0), fused split ----
        add_ln_split_k<<<dim3(SEQ), b256, 0, stream>>>(
            z2, x0, g1 + l * FDIM, be1 + l * FDIM, x1, X1h, X1l);

        // ---- FFN collapse: Pt = (W1@W2)^T via W2^T @ W1^T; bvec = b1@W2 + b2 ----
        tsplit(W2_l, DIM, HDIM, DIM, Wth, Wtl);              // W2^T [512][2048] (A)
        split(W1_l, HDIM, FDIM, HDIM, W1h, W1l);             // W1   [512][2048] (B)
        gemm(Wth, Wtl, W1h, W1l, nullptr, Pt,
             FDIM, FDIM, HDIM, HDIM, HDIM, DIM, 1.0f, 8);
        hipMemcpyAsync(bvec, b2 + l * DIM, DIM * 4, hipMemcpyDeviceToDevice, stream);
        bvec_k<<<dim3(DIM / 128, HDIM / 128), b256, 0, stream>>>(b1 + l * HDIM, W2_l, bvec);
        split(Pt, DIM, FDIM, DIM, Pth, Ptl);                 // B[do][f] = Pt

        // ---- h2 = x1 @ (W1@W2) + bvec ----
        gemm(X1h, X1l, Pth, Ptl, bvec, z2,
             SEQ, DIM, FDIM, DIM, DIM, DIM, 1.0f, 4);

        // ---- x0 = LN(h2 + x1), fused split ----
        add_ln_split_k<<<dim3(SEQ), b256, 0, stream>>>(
            z2, x1, g2 + l * DIM, be2 + l * DIM, x0, X0h, X0l);
    }

    // logits = x0 @ Wf + bf, chunked over vocab columns; then row softmax
    for (int n0 = 0; n0 < VOCAB; n0 += 8192) {
        const int nc = (VOCAB - n0 < 8192) ? (VOCAB - n0) : 8192;   // 8192/7424
        tsplit(Wf + n0, VOCAB, DIM, nc, Wth, Wtl);                  // [nc][512]
        gemm_bf16x3_k<<<dim3(nc / 128, SEQ / 128, 1), b256, 0, stream>>>(
            X0h, X0l, Wth, Wtl, bf + n0, out + n0, DIM, DIM, DIM, VOCAB, 1.0f, 1);
    }
    softmax_rows_k<<<dim3(SEQ), b1024, 0, stream>>>(out);
}

// Round 3
// 1687.497 us; speedup vs baseline: 1.4206x; 1.1268x over previous
//
#include <hip/hip_runtime.h>
#include <cmath>

#define SEQ 2048
#define DIM 512
#define FDIM 512
#define HDIM 2048
#define VOCAB 32000
#define NLAYER 4
#define LNEPS 1e-5f

typedef unsigned short ushort_t;
typedef __attribute__((ext_vector_type(8))) short short8;
typedef __attribute__((ext_vector_type(4))) float f32x4;

// ---------- bf16 helpers (RNE) ----------
__device__ __forceinline__ ushort_t f2bf(float x) {
    union { float f; unsigned int u; } a; a.f = x;
    unsigned int r = a.u + 0x7fffu + ((a.u >> 16) & 1u);
    return (ushort_t)(r >> 16);
}
__device__ __forceinline__ float bf2f(ushort_t b) {
    union { unsigned int u; float f; } a; a.u = ((unsigned int)b) << 16; return a.f;
}

// ---------- async global->LDS 16B ----------
__device__ __forceinline__ void gload_lds16(const ushort_t* g, ushort_t* l) {
    __builtin_amdgcn_global_load_lds(
        (const __attribute__((address_space(1))) void*)g,
        (__attribute__((address_space(3))) void*)l, 16, 0, 0);
}

// =====================================================================
// Shared GEMM core: stages A[M][K](lda),B[N][K](ldb) hi/lo tiles and
// accumulates 3x MFMA (hh, hl, lh). 128x128 tile, BK=32, 4 waves.
// =====================================================================
#define GEMM_CORE(AH, AL, BH, BL, LDA, LDB, KSTEPS, KBASE)                         \
    __shared__ ushort_t lds[16384];                                                \
    ushort_t* ldsAh = lds;                                                         \
    ushort_t* ldsAl = lds + 4096;                                                  \
    ushort_t* ldsBh = lds + 8192;                                                  \
    ushort_t* ldsBl = lds + 12288;                                                 \
    const int tid  = threadIdx.x;                                                  \
    const int lane = tid & 63, wv = tid >> 6;                                      \
    const int wm = wv >> 1, wn = wv & 1;                                           \
    const int q = lane >> 4, mlo = lane & 15;                                      \
    const int tm = blockIdx.y << 7, tn = blockIdx.x << 7;                          \
    f32x4 acc[4][4];                                                               \
    _Pragma("unroll")                                                              \
    for (int i = 0; i < 4; i++)                                                    \
        _Pragma("unroll")                                                          \
        for (int j = 0; j < 4; j++)                                                \
            acc[i][j] = (f32x4){0.f, 0.f, 0.f, 0.f};                               \
    for (int ks = 0; ks < (KSTEPS); ks++) {                                        \
        const int k0 = (KBASE) + (ks << 5);                                        \
        _Pragma("unroll")                                                          \
        for (int r = 0; r < 2; r++) {                                              \
            const int c  = (r << 8) + (wv << 6) + lane;                            \
            const int i  = c & 127, kb = c >> 7;                                   \
            const int lofs = ((r << 8) + (wv << 6)) << 3;                          \
            const size_t aoff = (size_t)(tm + i) * (LDA) + k0 + (kb << 3);         \
            const size_t boff = (size_t)(tn + i) * (LDB) + k0 + (kb << 3);         \
            gload_lds16((AH) + aoff, ldsAh + lofs);                                \
            gload_lds16((AL) + aoff, ldsAl + lofs);                                \
            gload_lds16((BH) + boff, ldsBh + lofs);                                \
            gload_lds16((BL) + boff, ldsBl + lofs);                                \
        }                                                                          \
        __syncthreads();                                                           \
        short8 ah[4], al[4], bh[4], bl[4];                                         \
        _Pragma("unroll")                                                          \
        for (int t = 0; t < 4; t++) {                                              \
            const int ma = ((q << 7) + (wm << 6) + (t << 4) + mlo) << 3;           \
            const int nb = ((q << 7) + (wn << 6) + (t << 4) + mlo) << 3;           \
            ah[t] = *(const short8*)&ldsAh[ma];                                    \
            al[t] = *(const short8*)&ldsAl[ma];                                    \
            bh[t] = *(const short8*)&ldsBh[nb];                                    \
            bl[t] = *(const short8*)&ldsBl[nb];                                    \
        }                                                                          \
        _Pragma("unroll")                                                          \
        for (int i = 0; i < 4; i++)                                                \
            _Pragma("unroll")                                                      \
            for (int j = 0; j < 4; j++) {                                          \
                acc[i][j] = __builtin_amdgcn_mfma_f32_16x16x32_bf16(ah[i], bh[j], acc[i][j], 0, 0, 0); \
                acc[i][j] = __builtin_amdgcn_mfma_f32_16x16x32_bf16(ah[i], bl[j], acc[i][j], 0, 0, 0); \
                acc[i][j] = __builtin_amdgcn_mfma_f32_16x16x32_bf16(al[i], bh[j], acc[i][j], 0, 0, 0); \
            }                                                                      \
        __syncthreads();                                                           \
    }

// flags: bit0 = causal block-skip (scores), bit1 = causal K-clamp (att@V).
// Batched over layers: blockIdx.z = l*splitk + zz; operand ptrs advance by bs*.
__global__ __launch_bounds__(256) void gemm_bf16x3_k(
    const ushort_t* __restrict__ Ah, const ushort_t* __restrict__ Al,
    const ushort_t* __restrict__ Bh, const ushort_t* __restrict__ Bl,
    const float* __restrict__ bias, float* __restrict__ C,
    int K, int lda, int ldb, int ldc, float scale, int splitk, int flags,
    int bsA, int bsB, int bsC, int bsBias)
{
    const int bz = blockIdx.z;
    const int l  = bz / splitk, zz = bz - l * splitk;
    Ah += (size_t)l * bsA; Al += (size_t)l * bsA;
    Bh += (size_t)l * bsB; Bl += (size_t)l * bsB;
    C  += (size_t)l * bsC;
    if (bias != nullptr) bias += (size_t)l * bsBias;
    const int tmq = blockIdx.y << 7, tnq = blockIdx.x << 7;
    if ((flags & 1) && tnq > tmq + 127) return;       // fully-masked causal block
    int ksteps = (K >> 5) / splitk;
    const int kbase = zz * ksteps * 32;
    if (flags & 2) {                                  // att rows need k <= row
        const int rem = (tmq + 128 - kbase) >> 5;
        if (rem < ksteps) ksteps = rem;
        if (ksteps <= 0) return;                      // zz>0 only; no bias missed
    }
    GEMM_CORE(Ah, Al, Bh, Bl, lda, ldb, ksteps, kbase)
    const bool addb = (bias != nullptr) && (zz == 0);
#pragma unroll
    for (int ti = 0; ti < 4; ti++)
#pragma unroll
        for (int tj = 0; tj < 4; tj++) {
            const int col = tn + (wn << 6) + (tj << 4) + mlo;
            const float bb = addb ? bias[col] : 0.f;
#pragma unroll
            for (int r = 0; r < 4; r++) {
                const int row = tm + (wm << 6) + (ti << 4) + (q << 2) + r;
                const float v = acc[ti][tj][r] * scale + bb;
                if (splitk == 1) C[(size_t)row * ldc + col] = v;
                else atomicAdd(&C[(size_t)row * ldc + col], v);
            }
        }
}

// ---- split-output GEMM (splitk==1): epilogue writes bf16 hi/lo directly ----
__global__ __launch_bounds__(256) void gemm_bf16x3_sp_k(
    const ushort_t* __restrict__ Ah, const ushort_t* __restrict__ Al,
    const ushort_t* __restrict__ Bh, const ushort_t* __restrict__ Bl,
    const float* __restrict__ bias,
    ushort_t* __restrict__ Dh, ushort_t* __restrict__ Dl,
    int K, int lda, int ldb, int ldo)
{
    GEMM_CORE(Ah, Al, Bh, Bl, lda, ldb, (K >> 5), 0)
#pragma unroll
    for (int ti = 0; ti < 4; ti++)
#pragma unroll
        for (int tj = 0; tj < 4; tj++) {
            const int col = tn + (wn << 6) + (tj << 4) + mlo;
            const float bb = (bias != nullptr) ? bias[col] : 0.f;
#pragma unroll
            for (int r = 0; r < 4; r++) {
                const int row = tm + (wm << 6) + (ti << 4) + (q << 2) + r;
                const float v = acc[ti][tj][r] + bb;
                const ushort_t h = f2bf(v);
                Dh[(size_t)row * ldo + col] = h;
                Dl[(size_t)row * ldo + col] = f2bf(v - bf2f(h));
            }
        }
}

// ---------- split fp32[R][C](ld) -> compact bf16 hi/lo [R][C] ----------
__global__ __launch_bounds__(128) void split_k(
    const float* __restrict__ src, int ld, int C,
    ushort_t* __restrict__ dh, ushort_t* __restrict__ dl)
{
    const int row = blockIdx.y;
    const int c4 = ((blockIdx.x << 7) + threadIdx.x) << 2;
    if (c4 >= C) return;
    const float4 v = *(const float4*)&src[(size_t)row * ld + c4];
    ushort_t h[4], l[4];
    const float f[4] = {v.x, v.y, v.z, v.w};
#pragma unroll
    for (int i = 0; i < 4; i++) {
        h[i] = f2bf(f[i]);
        l[i] = f2bf(f[i] - bf2f(h[i]));
    }
    *(ushort4*)&dh[(size_t)row * C + c4] = make_ushort4(h[0], h[1], h[2], h[3]);
    *(ushort4*)&dl[(size_t)row * C + c4] = make_ushort4(l[0], l[1], l[2], l[3]);
}

// ---------- transpose+split fp32[R][C](ld) -> bf16 hi/lo [C][R] ----------
__global__ __launch_bounds__(256) void tsplit_k(
    const float* __restrict__ src, int ld, int R,
    ushort_t* __restrict__ dh, ushort_t* __restrict__ dl)
{
    __shared__ float t[32][33];
    const int c = threadIdx.x & 31, r8 = threadIdx.x >> 5;
    const int bx = blockIdx.x, by = blockIdx.y;
#pragma unroll
    for (int i = 0; i < 4; i++) {
        const int r = (r8 << 2) + i;
        t[r][c] = src[(size_t)((by << 5) + r) * ld + (bx << 5) + c];
    }
    __syncthreads();
#pragma unroll
    for (int i = 0; i < 4; i++) {
        const int rr = (r8 << 2) + i;            // output row' = bx*32+rr
        const float v = t[c][rr];                // src[by*32+c][bx*32+rr]
        const ushort_t h = f2bf(v);
        const ushort_t l = f2bf(v - bf2f(h));
        const size_t o = (size_t)((bx << 5) + rr) * R + (by << 5) + c;
        dh[o] = h; dl[o] = l;
    }
}

// ---------- layer-batched transpose+split (blockIdx.z = layer) ----------
__global__ __launch_bounds__(256) void tsplit_b_k(
    const float* __restrict__ src0, int ld, int R, int sbs,
    ushort_t* __restrict__ dh0, ushort_t* __restrict__ dl0, int dbs)
{
    const int lz = blockIdx.z;
    const float* src = src0 + (size_t)lz * sbs;
    ushort_t* dh = dh0 + (size_t)lz * dbs;
    ushort_t* dl = dl0 + (size_t)lz * dbs;
    __shared__ float t[32][33];
    const int c = threadIdx.x & 31, r8 = threadIdx.x >> 5;
    const int bx = blockIdx.x, by = blockIdx.y;
#pragma unroll
    for (int i = 0; i < 4; i++) {
        const int r = (r8 << 2) + i;
        t[r][c] = src[(size_t)((by << 5) + r) * ld + (bx << 5) + c];
    }
    __syncthreads();
#pragma unroll
    for (int i = 0; i < 4; i++) {
        const int rr = (r8 << 2) + i;
        const float v = t[c][rr];
        const ushort_t h = f2bf(v);
        const ushort_t l = f2bf(v - bf2f(h));
        const size_t o = (size_t)((bx << 5) + rr) * R + (by << 5) + c;
        dh[o] = h; dl[o] = l;
    }
}

// ---------- gather merged qkv bias for all layers [L*1536] ----------
__global__ void gatherqkv_k(const float* bq, const float* bk, const float* bv, float* d)
{
    const int i = blockIdx.x * 256 + threadIdx.x;
    if (i >= NLAYER * 1536) return;
    const int l = i / 1536, j = i - l * 1536;
    float v;
    if (j < 512)       v = bq[l * 512 + j];
    else if (j < 1024) v = bk[l * 512 + j - 512];
    else               v = bv[l * 512 + j - 1024];
    d[i] = v;
}

// ---------- bvec[l] = b1[l] @ W2[l] + b2[l] (pre-initialized to b2) ----------
__global__ __launch_bounds__(256) void bvec_k(
    const float* __restrict__ b1, const float* __restrict__ W2,
    float* __restrict__ bv)
{
    const int lz = blockIdx.z;
    b1 += (size_t)lz * HDIM;
    W2 += (size_t)lz * HDIM * DIM;
    bv += (size_t)lz * DIM;
    const int c  = (blockIdx.x << 7) + (threadIdx.x & 127);
    const int h0 = (blockIdx.y << 7) + (threadIdx.x >> 7);
    float acc = 0.f;
#pragma unroll 8
    for (int i = 0; i < 64; i++) {
        const int h = h0 + (i << 1);
        acc += b1[h] * W2[(size_t)h * DIM + c];
    }
    atomicAdd(&bv[c], acc);
}

// ---------- causal softmax over rows of sc[S,S], fused bf16 hi/lo split out ----------
__global__ __launch_bounds__(256) void softmax_causal_split_k(
    const float* __restrict__ sc, ushort_t* __restrict__ dh, ushort_t* __restrict__ dl)
{
    const int i = blockIdx.x;
    const float* row = sc + (size_t)i * SEQ;
    const int tid = threadIdx.x;
    __shared__ float red[4];
    const int base = tid << 2;

    float4 v[2];
    v[0] = *(const float4*)&row[base];
    v[1] = *(const float4*)&row[1024 + base];

    float m = -3.402823466e38f;
#pragma unroll
    for (int c = 0; c < 2; c++) {
        float* f = (float*)&v[c];
        const int idx = (c << 10) + base;
#pragma unroll
        for (int j = 0; j < 4; j++) {
            if (idx + j > i) f[j] = -3.402823466e38f;   // causal mask
            m = fmaxf(m, f[j]);
        }
    }
#pragma unroll
    for (int o = 32; o > 0; o >>= 1) m = fmaxf(m, __shfl_down(m, o, 64));
    if ((tid & 63) == 0) red[tid >> 6] = m;
    __syncthreads();
    m = fmaxf(fmaxf(red[0], red[1]), fmaxf(red[2], red[3]));
    __syncthreads();

    float s = 0.f;
#pragma unroll
    for (int c = 0; c < 2; c++) {
        float* f = (float*)&v[c];
#pragma unroll
        for (int j = 0; j < 4; j++) {
            f[j] = expf(f[j] - m);     // masked lanes: expf(~-3.4e38) == 0
            s += f[j];
        }
    }
#pragma unroll
    for (int o = 32; o > 0; o >>= 1) s += __shfl_down(s, o, 64);
    if ((tid & 63) == 0) red[tid >> 6] = s;
    __syncthreads();
    const float inv = 1.0f / (red[0] + red[1] + red[2] + red[3]);

#pragma unroll
    for (int c = 0; c < 2; c++) {
        float* f = (float*)&v[c];
        const int idx = (c << 10) + base;
        ushort_t hp[4], lp[4];
#pragma unroll
        for (int j = 0; j < 4; j++) {
            const float e = f[j] * inv;         // masked -> exactly 0
            hp[j] = f2bf(e);
            lp[j] = f2bf(e - bf2f(hp[j]));
        }
        *(ushort4*)&dh[(size_t)i * SEQ + idx] = make_ushort4(hp[0], hp[1], hp[2], hp[3]);
        *(ushort4*)&dl[(size_t)i * SEQ + idx] = make_ushort4(lp[0], lp[1], lp[2], lp[3]);
    }
}

// ---------- out = LN(z + res) * g + b, fused bf16 hi/lo split out (width 512) ----------
__global__ __launch_bounds__(256) void add_ln_split_k(
    const float* __restrict__ z, const float* __restrict__ res,
    const float* __restrict__ g, const float* __restrict__ b,
    float* __restrict__ outp, ushort_t* __restrict__ dh, ushort_t* __restrict__ dl)
{
    const int row = blockIdx.x;
    const int tid = threadIdx.x;
    __shared__ float red[4];
    const size_t base = (size_t)row * DIM;
    const float v0 = z[base + tid] + res[base + tid];
    const float v1 = z[base + tid + 256] + res[base + tid + 256];
    float s = v0 + v1;
#pragma unroll
    for (int o = 32; o > 0; o >>= 1) s += __shfl_down(s, o, 64);
    if ((tid & 63) == 0) red[tid >> 6] = s;
    __syncthreads();
    const float mean = (red[0] + red[1] + red[2] + red[3]) * (1.0f / DIM);
    __syncthreads();
    const float d0 = v0 - mean, d1 = v1 - mean;
    float vs = d0 * d0 + d1 * d1;
#pragma unroll
    for (int o = 32; o > 0; o >>= 1) vs += __shfl_down(vs, o, 64);
    if ((tid & 63) == 0) red[tid >> 6] = vs;
    __syncthreads();
    const float var = (red[0] + red[1] + red[2] + red[3]) * (1.0f / DIM);
    const float inv = 1.0f / sqrtf(var + LNEPS);
    const float o0 = d0 * inv * g[tid] + b[tid];
    const float o1 = d1 * inv * g[tid + 256] + b[tid + 256];
    outp[base + tid]       = o0;
    outp[base + tid + 256] = o1;
    const ushort_t h0 = f2bf(o0), h1 = f2bf(o1);
    dh[base + tid]       = h0;  dl[base + tid]       = f2bf(o0 - bf2f(h0));
    dh[base + tid + 256] = h1;  dl[base + tid + 256] = f2bf(o1 - bf2f(h1));
}

// ---------- final row softmax over VOCAB: single-pass, register-resident ----------
__global__ __launch_bounds__(1024) void softmax_rows_k(float* __restrict__ p)
{
    const int row = blockIdx.x;
    float* r = p + (size_t)row * VOCAB;
    const int tid = threadIdx.x;
    __shared__ float red[16];
    const int base = tid << 2;

    float4 v[8];
#pragma unroll
    for (int c = 0; c < 7; c++) v[c] = *(const float4*)&r[(c << 12) + base];
    const bool tail = (28672 + base) < VOCAB;
    if (tail) v[7] = *(const float4*)&r[28672 + base];
    else { v[7].x = v[7].y = v[7].z = v[7].w = -3.402823466e38f; }

    float m = -3.402823466e38f;
#pragma unroll
    for (int c = 0; c < 8; c++)
        m = fmaxf(m, fmaxf(fmaxf(v[c].x, v[c].y), fmaxf(v[c].z, v[c].w)));
#pragma unroll
    for (int o = 32; o > 0; o >>= 1) m = fmaxf(m, __shfl_down(m, o, 64));
    if ((tid & 63) == 0) red[tid >> 6] = m;
    __syncthreads();
    m = red[0];
#pragma unroll
    for (int w = 1; w < 16; w++) m = fmaxf(m, red[w]);
    __syncthreads();

    float s = 0.f;
#pragma unroll
    for (int c = 0; c < 8; c++) {
        float* f = (float*)&v[c];
#pragma unroll
        for (int j = 0; j < 4; j++) {
            f[j] = expf(f[j] - m);
            s += f[j];
        }
    }
#pragma unroll
    for (int o = 32; o > 0; o >>= 1) s += __shfl_down(s, o, 64);
    if ((tid & 63) == 0) red[tid >> 6] = s;
    __syncthreads();
    float tot = 0.f;
#pragma unroll
    for (int w = 0; w < 16; w++) tot += red[w];
    const float inv = 1.0f / tot;

#pragma unroll
    for (int c = 0; c < 7; c++) {
        float4 o4;
        o4.x = v[c].x * inv; o4.y = v[c].y * inv;
        o4.z = v[c].z * inv; o4.w = v[c].w * inv;
        *(float4*)&r[(c << 12) + base] = o4;
    }
    if (tail) {
        float4 o4;
        o4.x = v[7].x * inv; o4.y = v[7].y * inv;
        o4.z = v[7].z * inv; o4.w = v[7].w * inv;
        *(float4*)&r[28672 + base] = o4;
    }
}

extern "C" void kernel_launch(void* const* d_in, const int* in_sizes, int n_in,
                              void* d_out, int out_size, void* d_ws, size_t ws_size,
                              hipStream_t stream)
{
    const float* x   = (const float*)d_in[0];
    const float* Wq  = (const float*)d_in[1];
    const float* bq  = (const float*)d_in[2];
    const float* Wk  = (const float*)d_in[3];
    const float* bk  = (const float*)d_in[4];
    const float* Wv  = (const float*)d_in[5];
    const float* bv  = (const float*)d_in[6];
    const float* Wp  = (const float*)d_in[7];
    const float* bp  = (const float*)d_in[8];
    const float* g1  = (const float*)d_in[9];
    const float* be1 = (const float*)d_in[10];
    const float* W1  = (const float*)d_in[11];
    const float* b1  = (const float*)d_in[12];
    const float* W2  = (const float*)d_in[13];
    const float* b2  = (const float*)d_in[14];
    const float* g2  = (const float*)d_in[15];
    const float* be2 = (const float*)d_in[16];
    const float* Wf  = (const float*)d_in[17];
    const float* bf  = (const float*)d_in[18];
    float* out = (float*)d_out;

    // ---- workspace carve (aligned 256B) ----
    char* ws = (char*)d_ws;
    auto alloc = [&](size_t bytes) {
        void* p = ws;
        ws += (bytes + 255) & ~(size_t)255;
        return p;
    };
    float*    x0     = (float*)alloc((size_t)SEQ * DIM * 4);
    float*    x1     = (float*)alloc((size_t)SEQ * DIM * 4);
    float*    vp     = (float*)alloc((size_t)SEQ * FDIM * 4);
    float*    z2     = (float*)alloc((size_t)SEQ * FDIM * 4);
    float*    sc     = (float*)alloc((size_t)SEQ * SEQ * 4);
    float*    PtA    = (float*)alloc((size_t)NLAYER * FDIM * DIM * 4);     // (W1@W2)^T all layers
    ushort_t* QKVh   = (ushort_t*)alloc((size_t)SEQ * 1536 * 2);
    ushort_t* QKVl   = (ushort_t*)alloc((size_t)SEQ * 1536 * 2);
    ushort_t* X0h    = (ushort_t*)alloc((size_t)SEQ * DIM * 2);
    ushort_t* X0l    = (ushort_t*)alloc((size_t)SEQ * DIM * 2);
    ushort_t* X1h    = (ushort_t*)alloc((size_t)SEQ * DIM * 2);
    ushort_t* X1l    = (ushort_t*)alloc((size_t)SEQ * DIM * 2);
    ushort_t* AttH   = (ushort_t*)alloc((size_t)SEQ * SEQ * 2);
    ushort_t* AttL   = (ushort_t*)alloc((size_t)SEQ * SEQ * 2);
    ushort_t* Wbh    = (ushort_t*)alloc((size_t)NLAYER * 1536 * 512 * 2); // [Wq;Wk;Wv]^T
    ushort_t* Wbl    = (ushort_t*)alloc((size_t)NLAYER * 1536 * 512 * 2);
    ushort_t* WpTh   = (ushort_t*)alloc((size_t)NLAYER * 512 * 512 * 2);
    ushort_t* WpTl   = (ushort_t*)alloc((size_t)NLAYER * 512 * 512 * 2);
    ushort_t* W2th   = (ushort_t*)alloc((size_t)NLAYER * 512 * 2048 * 2);
    ushort_t* W2tl   = (ushort_t*)alloc((size_t)NLAYER * 512 * 2048 * 2);
    ushort_t* W1h    = (ushort_t*)alloc((size_t)NLAYER * 512 * 2048 * 2);
    ushort_t* W1l    = (ushort_t*)alloc((size_t)NLAYER * 512 * 2048 * 2);
    ushort_t* Pth    = (ushort_t*)alloc((size_t)NLAYER * 512 * 512 * 2);
    ushort_t* Ptl    = (ushort_t*)alloc((size_t)NLAYER * 512 * 512 * 2);
    ushort_t* VpTh   = (ushort_t*)alloc((size_t)FDIM * SEQ * 2);
    ushort_t* VpTl   = (ushort_t*)alloc((size_t)FDIM * SEQ * 2);
    ushort_t* Wfh    = (ushort_t*)alloc((size_t)VOCAB * DIM * 2);
    ushort_t* Wfl    = (ushort_t*)alloc((size_t)VOCAB * DIM * 2);
    float*    bqkvA  = (float*)alloc((size_t)NLAYER * 1536 * 4);
    float*    bvecA  = (float*)alloc((size_t)NLAYER * DIM * 4);

    const float att_scale = 1.0f / sqrtf((float)FDIM);
    const dim3 b256(256), b128(128), b1024(1024);

    auto split = [&](const float* src, int ld, int R, int C, ushort_t* dh, ushort_t* dl) {
        split_k<<<dim3((C / 4 + 127) / 128, R), b128, 0, stream>>>(src, ld, C, dh, dl);
    };
    auto gemm = [&](const ushort_t* ah, const ushort_t* al,
                    const ushort_t* bh, const ushort_t* bl,
                    const float* bias, float* C, int M, int N, int K,
                    int lda, int ldb, int ldc, float scale, int splitk, int flags) {
        if (splitk > 1)
            hipMemsetAsync(C, 0, (size_t)M * ldc * 4, stream);
        gemm_bf16x3_k<<<dim3(N / 128, M / 128, splitk), b256, 0, stream>>>(
            ah, al, bh, bl, bias, C, K, lda, ldb, ldc, scale, splitk, flags, 0, 0, 0, 0);
    };

    // ================= weight prep (all layers, batched) =================
    hipMemcpyAsync(x0, x, (size_t)SEQ * DIM * 4, hipMemcpyDeviceToDevice, stream);
    // [Wq;Wk;Wv]^T per layer -> Wb[l][1536][512]
    tsplit_b_k<<<dim3(16, 16, NLAYER), b256, 0, stream>>>(Wq, FDIM, DIM, 262144, Wbh, Wbl, 786432);
    tsplit_b_k<<<dim3(16, 16, NLAYER), b256, 0, stream>>>(Wk, FDIM, DIM, 262144, Wbh + 262144, Wbl + 262144, 786432);
    tsplit_b_k<<<dim3(16, 16, NLAYER), b256, 0, stream>>>(Wv, FDIM, DIM, 262144, Wbh + 524288, Wbl + 524288, 786432);
    // Wp^T per layer
    tsplit_b_k<<<dim3(16, 16, NLAYER), b256, 0, stream>>>(Wp, FDIM, FDIM, 262144, WpTh, WpTl, 262144);
    // W2^T per layer [512][2048]
    tsplit_b_k<<<dim3(16, 64, NLAYER), b256, 0, stream>>>(W2, DIM, HDIM, HDIM * DIM, W2th, W2tl, 1048576);
    // W1 rows (all layers contiguous) [L*512][2048]
    split(W1, HDIM, NLAYER * FDIM, HDIM, W1h, W1l);
    // Pt[l] = (W1@W2)^T : batched GEMM, splitk=8
    hipMemsetAsync(PtA, 0, (size_t)NLAYER * FDIM * DIM * 4, stream);
    gemm_bf16x3_k<<<dim3(4, 4, NLAYER * 8), b256, 0, stream>>>(
        W2th, W2tl, W1h, W1l, nullptr, PtA, HDIM, HDIM, HDIM, DIM, 1.0f, 8, 0,
        1048576, 1048576, 262144, 0);
    split(PtA, DIM, NLAYER * FDIM, DIM, Pth, Ptl);
    // biases
    gatherqkv_k<<<dim3((NLAYER * 1536 + 255) / 256), b256, 0, stream>>>(bq, bk, bv, bqkvA);
    hipMemcpyAsync(bvecA, b2, (size_t)NLAYER * DIM * 4, hipMemcpyDeviceToDevice, stream);
    bvec_k<<<dim3(4, 16, NLAYER), b256, 0, stream>>>(b1, W2, bvecA);
    // Wf^T whole [32000][512]
    tsplit_k<<<dim3(VOCAB / 32, DIM / 32), b256, 0, stream>>>(Wf, VOCAB, DIM, Wfh, Wfl);
    // initial split of x
    split(x0, DIM, SEQ, DIM, X0h, X0l);

    // ================= layers =================
    for (int l = 0; l < NLAYER; l++) {
        // QKV (split-out epilogue)
        gemm_bf16x3_sp_k<<<dim3(12, 16), b256, 0, stream>>>(
            X0h, X0l, Wbh + (size_t)l * 786432, Wbl + (size_t)l * 786432,
            bqkvA + (size_t)l * 1536, QKVh, QKVl, DIM, DIM, DIM, 1536);

        // Vp = v @ Wp (bias bp deferred to z2 epilogue)
        gemm(QKVh + 1024, QKVl + 1024, WpTh + (size_t)l * 262144, WpTl + (size_t)l * 262144,
             nullptr, vp, SEQ, FDIM, FDIM, 1536, FDIM, FDIM, 1.0f, 4, 0);

        // scores = scale * q @ k^T (causal block-skip); softmax fused split
        gemm(QKVh, QKVl, QKVh + 512, QKVl + 512, nullptr, sc,
             SEQ, SEQ, FDIM, 1536, 1536, SEQ, att_scale, 2, 1);
        softmax_causal_split_k<<<dim3(SEQ), b256, 0, stream>>>(sc, AttH, AttL);

        // z2 = att @ Vp + bp (causal K-clamp)
        tsplit_k<<<dim3(16, 64), b256, 0, stream>>>(vp, FDIM, SEQ, VpTh, VpTl);
        gemm(AttH, AttL, VpTh, VpTl, bp + l * FDIM, z2,
             SEQ, FDIM, SEQ, SEQ, SEQ, FDIM, 1.0f, 4, 2);

        // x1 = LN(z2 + x0), fused split
        add_ln_split_k<<<dim3(SEQ), b256, 0, stream>>>(
            z2, x0, g1 + l * FDIM, be1 + l * FDIM, x1, X1h, X1l);

        // h2 = x1 @ (W1@W2) + bvec
        gemm(X1h, X1l, Pth + (size_t)l * 262144, Ptl + (size_t)l * 262144,
             bvecA + (size_t)l * DIM, z2, SEQ, DIM, FDIM, DIM, DIM, DIM, 1.0f, 4, 0);

        // x0 = LN(h2 + x1), fused split
        add_ln_split_k<<<dim3(SEQ), b256, 0, stream>>>(
            z2, x1, g2 + l * DIM, be2 + l * DIM, x0, X0h, X0l);
    }

    // logits = x0 @ Wf + bf (single launch), then row softmax
    gemm_bf16x3_k<<<dim3(VOCAB / 128, SEQ / 128, 1), b256, 0, stream>>>(
        X0h, X0l, Wfh, Wfl, bf, out, DIM, DIM, DIM, VOCAB, 1.0f, 1, 0, 0, 0, 0, 0);
    softmax_rows_k<<<dim3(SEQ), b1024, 0, stream>>>(out);
}

// Round 4
// 1514.071 us; speedup vs baseline: 1.5833x; 1.1145x over previous
//
#include <hip/hip_runtime.h>
#include <cmath>

#define SEQ 2048
#define DIM 512
#define FDIM 512
#define HDIM 2048
#define VOCAB 32000
#define NLAYER 4
#define LNEPS 1e-5f

typedef unsigned short ushort_t;
typedef __attribute__((ext_vector_type(8))) short short8;
typedef __attribute__((ext_vector_type(4))) float f32x4;

// ---------- bf16 helpers (RNE) ----------
__device__ __forceinline__ ushort_t f2bf(float x) {
    union { float f; unsigned int u; } a; a.f = x;
    unsigned int r = a.u + 0x7fffu + ((a.u >> 16) & 1u);
    return (ushort_t)(r >> 16);
}
__device__ __forceinline__ float bf2f(ushort_t b) {
    union { unsigned int u; float f; } a; a.u = ((unsigned int)b) << 16; return a.f;
}

// ---------- async global->LDS 16B ----------
__device__ __forceinline__ void gload_lds16(const ushort_t* g, ushort_t* l) {
    __builtin_amdgcn_global_load_lds(
        (const __attribute__((address_space(1))) void*)g,
        (__attribute__((address_space(3))) void*)l, 16, 0, 0);
}

// =====================================================================
// Shared GEMM core: stages A[M][K](lda),B[N][K](ldb) hi/lo tiles and
// accumulates 3x MFMA (hh, hl, lh). 128x128 tile, BK=32, 4 waves.
// =====================================================================
#define GEMM_CORE(AH, AL, BH, BL, LDA, LDB, KSTEPS, KBASE, TM, TN)                 \
    __shared__ ushort_t lds[16384];                                                \
    ushort_t* ldsAh = lds;                                                         \
    ushort_t* ldsAl = lds + 4096;                                                  \
    ushort_t* ldsBh = lds + 8192;                                                  \
    ushort_t* ldsBl = lds + 12288;                                                 \
    const int tid  = threadIdx.x;                                                  \
    const int lane = tid & 63, wv = tid >> 6;                                      \
    const int wm = wv >> 1, wn = wv & 1;                                           \
    const int q = lane >> 4, mlo = lane & 15;                                      \
    const int tm = (TM), tn = (TN);                                                \
    f32x4 acc[4][4];                                                               \
    _Pragma("unroll")                                                              \
    for (int i = 0; i < 4; i++)                                                    \
        _Pragma("unroll")                                                          \
        for (int j = 0; j < 4; j++)                                                \
            acc[i][j] = (f32x4){0.f, 0.f, 0.f, 0.f};                               \
    for (int ks = 0; ks < (KSTEPS); ks++) {                                        \
        const int k0 = (KBASE) + (ks << 5);                                        \
        _Pragma("unroll")                                                          \
        for (int r = 0; r < 2; r++) {                                              \
            const int c  = (r << 8) + (wv << 6) + lane;                            \
            const int i  = c & 127, kb = c >> 7;                                   \
            const int lofs = ((r << 8) + (wv << 6)) << 3;                          \
            const size_t aoff = (size_t)(tm + i) * (LDA) + k0 + (kb << 3);         \
            const size_t boff = (size_t)(tn + i) * (LDB) + k0 + (kb << 3);         \
            gload_lds16((AH) + aoff, ldsAh + lofs);                                \
            gload_lds16((AL) + aoff, ldsAl + lofs);                                \
            gload_lds16((BH) + boff, ldsBh + lofs);                                \
            gload_lds16((BL) + boff, ldsBl + lofs);                                \
        }                                                                          \
        __syncthreads();                                                           \
        short8 ah[4], al[4], bh[4], bl[4];                                         \
        _Pragma("unroll")                                                          \
        for (int t = 0; t < 4; t++) {                                              \
            const int ma = ((q << 7) + (wm << 6) + (t << 4) + mlo) << 3;           \
            const int nb = ((q << 7) + (wn << 6) + (t << 4) + mlo) << 3;           \
            ah[t] = *(const short8*)&ldsAh[ma];                                    \
            al[t] = *(const short8*)&ldsAl[ma];                                    \
            bh[t] = *(const short8*)&ldsBh[nb];                                    \
            bl[t] = *(const short8*)&ldsBl[nb];                                    \
        }                                                                          \
        _Pragma("unroll")                                                          \
        for (int i = 0; i < 4; i++)                                                \
            _Pragma("unroll")                                                      \
            for (int j = 0; j < 4; j++) {                                          \
                acc[i][j] = __builtin_amdgcn_mfma_f32_16x16x32_bf16(ah[i], bh[j], acc[i][j], 0, 0, 0); \
                acc[i][j] = __builtin_amdgcn_mfma_f32_16x16x32_bf16(ah[i], bl[j], acc[i][j], 0, 0, 0); \
                acc[i][j] = __builtin_amdgcn_mfma_f32_16x16x32_bf16(al[i], bh[j], acc[i][j], 0, 0, 0); \
            }                                                                      \
        __syncthreads();                                                           \
    }

// flags: bit0 = causal block-skip (scores), bit1 = causal K-clamp (att@V),
//        bit2 = swap grid x/y (M-tiles consecutive -> B-panel L2 reuse).
// splitk>1: bsPart!=0 -> write partial buffers C + zz*bsPart (no atomics);
//           bsPart==0 -> atomicAdd into pre-zeroed C.
// Batched over layers: blockIdx.z = l*splitk + zz; ptrs advance by bs*.
__global__ __launch_bounds__(256) void gemm_bf16x3_k(
    const ushort_t* __restrict__ Ah, const ushort_t* __restrict__ Al,
    const ushort_t* __restrict__ Bh, const ushort_t* __restrict__ Bl,
    const float* __restrict__ bias, float* __restrict__ C,
    int K, int lda, int ldb, int ldc, float scale, int splitk, int flags,
    int bsA, int bsB, int bsC, int bsBias, int bsPart)
{
    const int bz = blockIdx.z;
    const int l  = bz / splitk, zz = bz - l * splitk;
    Ah += (size_t)l * bsA; Al += (size_t)l * bsA;
    Bh += (size_t)l * bsB; Bl += (size_t)l * bsB;
    C  += (size_t)l * bsC;
    if (bias != nullptr) bias += (size_t)l * bsBias;
    int bx = blockIdx.x, by = blockIdx.y;
    if (flags & 4) { const int t = bx; bx = by; by = t; }
    const int tmq = by << 7, tnq = bx << 7;
    if ((flags & 1) && tnq > tmq + 127) return;       // fully-masked causal block
    int ksteps = (K >> 5) / splitk;
    const int kbase = zz * ksteps * 32;
    if (flags & 2) {                                  // att rows need k <= row
        const int rem = (tmq + 128 - kbase) >> 5;
        if (rem < ksteps) ksteps = rem;
        if (ksteps <= 0) return;                      // consumer knows validity
    }
    GEMM_CORE(Ah, Al, Bh, Bl, lda, ldb, ksteps, kbase, tmq, tnq)
    const bool addb = (bias != nullptr) && (zz == 0);
    float* Cw = C + ((splitk > 1 && bsPart) ? (size_t)zz * bsPart : 0);
#pragma unroll
    for (int ti = 0; ti < 4; ti++)
#pragma unroll
        for (int tj = 0; tj < 4; tj++) {
            const int col = tn + (wn << 6) + (tj << 4) + mlo;
            const float bb = addb ? bias[col] : 0.f;
#pragma unroll
            for (int r = 0; r < 4; r++) {
                const int row = tm + (wm << 6) + (ti << 4) + (q << 2) + r;
                const float v = acc[ti][tj][r] * scale + bb;
                if (splitk == 1 || bsPart) Cw[(size_t)row * ldc + col] = v;
                else atomicAdd(&C[(size_t)row * ldc + col], v);
            }
        }
}

// ---- QKV GEMM: B = [Wq^T; Wk^T; Wvp^T] (1536x512). Epilogue writes
//      q,k as bf16 hi/lo [SEQ][1024]; vp (cols>=1024) TRANSPOSED [512][SEQ].
__global__ __launch_bounds__(256) void gemm_qkv_k(
    const ushort_t* __restrict__ Ah, const ushort_t* __restrict__ Al,
    const ushort_t* __restrict__ Bh, const ushort_t* __restrict__ Bl,
    const float* __restrict__ bias,
    ushort_t* __restrict__ QKh, ushort_t* __restrict__ QKl,
    ushort_t* __restrict__ Vh,  ushort_t* __restrict__ Vl)
{
    GEMM_CORE(Ah, Al, Bh, Bl, DIM, DIM, (DIM >> 5), 0,
              (int)(blockIdx.y << 7), (int)(blockIdx.x << 7))
#pragma unroll
    for (int ti = 0; ti < 4; ti++)
#pragma unroll
        for (int tj = 0; tj < 4; tj++) {
            const int col = tn + (wn << 6) + (tj << 4) + mlo;
            const float bb = bias[col];
#pragma unroll
            for (int r = 0; r < 4; r++) {
                const int row = tm + (wm << 6) + (ti << 4) + (q << 2) + r;
                const float v = acc[ti][tj][r] + bb;
                const ushort_t h = f2bf(v);
                const ushort_t lo = f2bf(v - bf2f(h));
                if (col < 1024) {
                    QKh[(size_t)row * 1024 + col] = h;
                    QKl[(size_t)row * 1024 + col] = lo;
                } else {
                    Vh[(size_t)(col - 1024) * SEQ + row] = h;
                    Vl[(size_t)(col - 1024) * SEQ + row] = lo;
                }
            }
        }
}

// ---------- split fp32[R][C](ld) -> compact bf16 hi/lo [R][C] ----------
__global__ __launch_bounds__(128) void split_k(
    const float* __restrict__ src, int ld, int C,
    ushort_t* __restrict__ dh, ushort_t* __restrict__ dl)
{
    const int row = blockIdx.y;
    const int c4 = ((blockIdx.x << 7) + threadIdx.x) << 2;
    if (c4 >= C) return;
    const float4 v = *(const float4*)&src[(size_t)row * ld + c4];
    ushort_t h[4], l[4];
    const float f[4] = {v.x, v.y, v.z, v.w};
#pragma unroll
    for (int i = 0; i < 4; i++) {
        h[i] = f2bf(f[i]);
        l[i] = f2bf(f[i] - bf2f(h[i]));
    }
    *(ushort4*)&dh[(size_t)row * C + c4] = make_ushort4(h[0], h[1], h[2], h[3]);
    *(ushort4*)&dl[(size_t)row * C + c4] = make_ushort4(l[0], l[1], l[2], l[3]);
}

// ---------- layer-batched plain split with dst stride ----------
__global__ __launch_bounds__(128) void split_b_k(
    const float* __restrict__ src0, int ld, int C, int sbs,
    ushort_t* __restrict__ dh0, ushort_t* __restrict__ dl0, int dbs)
{
    const int lz = blockIdx.z;
    const float* src = src0 + (size_t)lz * sbs;
    ushort_t* dh = dh0 + (size_t)lz * dbs;
    ushort_t* dl = dl0 + (size_t)lz * dbs;
    const int row = blockIdx.y;
    const int c4 = ((blockIdx.x << 7) + threadIdx.x) << 2;
    if (c4 >= C) return;
    const float4 v = *(const float4*)&src[(size_t)row * ld + c4];
    ushort_t h[4], l[4];
    const float f[4] = {v.x, v.y, v.z, v.w};
#pragma unroll
    for (int i = 0; i < 4; i++) {
        h[i] = f2bf(f[i]);
        l[i] = f2bf(f[i] - bf2f(h[i]));
    }
    *(ushort4*)&dh[(size_t)row * C + c4] = make_ushort4(h[0], h[1], h[2], h[3]);
    *(ushort4*)&dl[(size_t)row * C + c4] = make_ushort4(l[0], l[1], l[2], l[3]);
}

// ---------- transpose+split fp32[R][C](ld) -> bf16 hi/lo [C][R] ----------
__global__ __launch_bounds__(256) void tsplit_k(
    const float* __restrict__ src, int ld, int R,
    ushort_t* __restrict__ dh, ushort_t* __restrict__ dl)
{
    __shared__ float t[32][33];
    const int c = threadIdx.x & 31, r8 = threadIdx.x >> 5;
    const int bx = blockIdx.x, by = blockIdx.y;
#pragma unroll
    for (int i = 0; i < 4; i++) {
        const int r = (r8 << 2) + i;
        t[r][c] = src[(size_t)((by << 5) + r) * ld + (bx << 5) + c];
    }
    __syncthreads();
#pragma unroll
    for (int i = 0; i < 4; i++) {
        const int rr = (r8 << 2) + i;            // output row' = bx*32+rr
        const float v = t[c][rr];                // src[by*32+c][bx*32+rr]
        const ushort_t h = f2bf(v);
        const ushort_t l = f2bf(v - bf2f(h));
        const size_t o = (size_t)((bx << 5) + rr) * R + (by << 5) + c;
        dh[o] = h; dl[o] = l;
    }
}

// ---------- layer-batched transpose+split (blockIdx.z = layer) ----------
__global__ __launch_bounds__(256) void tsplit_b_k(
    const float* __restrict__ src0, int ld, int R, int sbs,
    ushort_t* __restrict__ dh0, ushort_t* __restrict__ dl0, int dbs)
{
    const int lz = blockIdx.z;
    const float* src = src0 + (size_t)lz * sbs;
    ushort_t* dh = dh0 + (size_t)lz * dbs;
    ushort_t* dl = dl0 + (size_t)lz * dbs;
    __shared__ float t[32][33];
    const int c = threadIdx.x & 31, r8 = threadIdx.x >> 5;
    const int bx = blockIdx.x, by = blockIdx.y;
#pragma unroll
    for (int i = 0; i < 4; i++) {
        const int r = (r8 << 2) + i;
        t[r][c] = src[(size_t)((by << 5) + r) * ld + (bx << 5) + c];
    }
    __syncthreads();
#pragma unroll
    for (int i = 0; i < 4; i++) {
        const int rr = (r8 << 2) + i;
        const float v = t[c][rr];
        const ushort_t h = f2bf(v);
        const ushort_t l = f2bf(v - bf2f(h));
        const size_t o = (size_t)((bx << 5) + rr) * R + (by << 5) + c;
        dh[o] = h; dl[o] = l;
    }
}

// ---------- gather merged qkv bias for all layers [L*1536] ----------
__global__ void gatherqkv_k(const float* bq, const float* bk, const float* bvp, float* d)
{
    const int i = blockIdx.x * 256 + threadIdx.x;
    if (i >= NLAYER * 1536) return;
    const int l = i / 1536, j = i - l * 1536;
    float v;
    if (j < 512)       v = bq[l * 512 + j];
    else if (j < 1024) v = bk[l * 512 + j - 512];
    else               v = bvp[l * 512 + j - 1024];
    d[i] = v;
}

// ---------- out[l][c] += vec[l] @ W[l] ; W is [H][512] rows, grid.y = H/128 ----------
__global__ __launch_bounds__(256) void bvecg_k(
    const float* __restrict__ vec, const float* __restrict__ W,
    float* __restrict__ outp, int sbsV, int sbsW)
{
    const int lz = blockIdx.z;
    vec  += (size_t)lz * sbsV;
    W    += (size_t)lz * sbsW;
    outp += (size_t)lz * DIM;
    const int c  = (blockIdx.x << 7) + (threadIdx.x & 127);
    const int h0 = (blockIdx.y << 7) + (threadIdx.x >> 7);
    float acc = 0.f;
#pragma unroll 8
    for (int i = 0; i < 64; i++) {
        const int h = h0 + (i << 1);
        acc += vec[h] * W[(size_t)h * DIM + c];
    }
    atomicAdd(&outp[c], acc);
}

// ---------- causal softmax over 2 K-partials of sc, fused bf16 hi/lo split out ----------
// Writes only k < ((row>>7)+1)*128 (the region the K-clamped att@V GEMM reads).
__global__ __launch_bounds__(256) void softmax_causal_split_k(
    const float* __restrict__ sc, ushort_t* __restrict__ dh, ushort_t* __restrict__ dl)
{
    const int i = blockIdx.x;
    const float* p0 = sc + (size_t)i * SEQ;
    const float* p1 = p0 + (size_t)SEQ * SEQ;
    const int tid = threadIdx.x;
    __shared__ float red[4];
    const int base = tid << 2;
    const int lim = ((i >> 7) + 1) << 7;

    float4 v[2];
#pragma unroll
    for (int c = 0; c < 2; c++) {
        const int idx = (c << 10) + base;
        const float4 a = *(const float4*)&p0[idx];
        const float4 b = *(const float4*)&p1[idx];
        v[c].x = a.x + b.x; v[c].y = a.y + b.y;
        v[c].z = a.z + b.z; v[c].w = a.w + b.w;
    }

    float m = -3.402823466e38f;
#pragma unroll
    for (int c = 0; c < 2; c++) {
        float* f = (float*)&v[c];
        const int idx = (c << 10) + base;
#pragma unroll
        for (int j = 0; j < 4; j++) {
            if (idx + j > i) f[j] = -3.402823466e38f;   // causal mask (kills garbage too)
            m = fmaxf(m, f[j]);
        }
    }
#pragma unroll
    for (int o = 32; o > 0; o >>= 1) m = fmaxf(m, __shfl_down(m, o, 64));
    if ((tid & 63) == 0) red[tid >> 6] = m;
    __syncthreads();
    m = fmaxf(fmaxf(red[0], red[1]), fmaxf(red[2], red[3]));
    __syncthreads();

    float s = 0.f;
#pragma unroll
    for (int c = 0; c < 2; c++) {
        float* f = (float*)&v[c];
#pragma unroll
        for (int j = 0; j < 4; j++) {
            f[j] = expf(f[j] - m);     // masked lanes: expf(~-3.4e38) == 0
            s += f[j];
        }
    }
#pragma unroll
    for (int o = 32; o > 0; o >>= 1) s += __shfl_down(s, o, 64);
    if ((tid & 63) == 0) red[tid >> 6] = s;
    __syncthreads();
    const float inv = 1.0f / (red[0] + red[1] + red[2] + red[3]);

#pragma unroll
    for (int c = 0; c < 2; c++) {
        float* f = (float*)&v[c];
        const int idx = (c << 10) + base;
        if (idx >= lim) continue;                // never read downstream
        ushort_t hp[4], lp[4];
#pragma unroll
        for (int j = 0; j < 4; j++) {
            const float e = f[j] * inv;          // masked -> exactly 0
            hp[j] = f2bf(e);
            lp[j] = f2bf(e - bf2f(hp[j]));
        }
        *(ushort4*)&dh[(size_t)i * SEQ + idx] = make_ushort4(hp[0], hp[1], hp[2], hp[3]);
        *(ushort4*)&dl[(size_t)i * SEQ + idx] = make_ushort4(lp[0], lp[1], lp[2], lp[3]);
    }
}

// ---------- out = LN(sum(zp partials) + res) * g + b, fused bf16 hi/lo split ----------
// clampk: attV K-clamped partials -> partial p valid iff p*512 <= row.
__global__ __launch_bounds__(256) void add_ln_split_k(
    const float* __restrict__ zp, const float* __restrict__ res,
    const float* __restrict__ g, const float* __restrict__ b,
    float* __restrict__ outp, ushort_t* __restrict__ dh, ushort_t* __restrict__ dl,
    int parts, int clampk)
{
    const int row = blockIdx.x;
    const int tid = threadIdx.x;
    __shared__ float red[4];
    const size_t base = (size_t)row * DIM;
    const size_t pst  = (size_t)SEQ * DIM;
    int np = clampk ? ((row >> 9) + 1) : parts;
    if (np > parts) np = parts;
    float v0 = res[base + tid];
    float v1 = res[base + tid + 256];
    for (int p = 0; p < np; p++) {
        v0 += zp[(size_t)p * pst + base + tid];
        v1 += zp[(size_t)p * pst + base + tid + 256];
    }
    float s = v0 + v1;
#pragma unroll
    for (int o = 32; o > 0; o >>= 1) s += __shfl_down(s, o, 64);
    if ((tid & 63) == 0) red[tid >> 6] = s;
    __syncthreads();
    const float mean = (red[0] + red[1] + red[2] + red[3]) * (1.0f / DIM);
    __syncthreads();
    const float d0 = v0 - mean, d1 = v1 - mean;
    float vs = d0 * d0 + d1 * d1;
#pragma unroll
    for (int o = 32; o > 0; o >>= 1) vs += __shfl_down(vs, o, 64);
    if ((tid & 63) == 0) red[tid >> 6] = vs;
    __syncthreads();
    const float var = (red[0] + red[1] + red[2] + red[3]) * (1.0f / DIM);
    const float inv = 1.0f / sqrtf(var + LNEPS);
    const float o0 = d0 * inv * g[tid] + b[tid];
    const float o1 = d1 * inv * g[tid + 256] + b[tid + 256];
    outp[base + tid]       = o0;
    outp[base + tid + 256] = o1;
    const ushort_t h0 = f2bf(o0), h1 = f2bf(o1);
    dh[base + tid]       = h0;  dl[base + tid]       = f2bf(o0 - bf2f(h0));
    dh[base + tid + 256] = h1;  dl[base + tid + 256] = f2bf(o1 - bf2f(h1));
}

// ---------- final row softmax over VOCAB: single-pass, register-resident ----------
__global__ __launch_bounds__(1024) void softmax_rows_k(float* __restrict__ p)
{
    const int row = blockIdx.x;
    float* r = p + (size_t)row * VOCAB;
    const int tid = threadIdx.x;
    __shared__ float red[16];
    const int base = tid << 2;

    float4 v[8];
#pragma unroll
    for (int c = 0; c < 7; c++) v[c] = *(const float4*)&r[(c << 12) + base];
    const bool tail = (28672 + base) < VOCAB;
    if (tail) v[7] = *(const float4*)&r[28672 + base];
    else { v[7].x = v[7].y = v[7].z = v[7].w = -3.402823466e38f; }

    float m = -3.402823466e38f;
#pragma unroll
    for (int c = 0; c < 8; c++)
        m = fmaxf(m, fmaxf(fmaxf(v[c].x, v[c].y), fmaxf(v[c].z, v[c].w)));
#pragma unroll
    for (int o = 32; o > 0; o >>= 1) m = fmaxf(m, __shfl_down(m, o, 64));
    if ((tid & 63) == 0) red[tid >> 6] = m;
    __syncthreads();
    m = red[0];
#pragma unroll
    for (int w = 1; w < 16; w++) m = fmaxf(m, red[w]);
    __syncthreads();

    float s = 0.f;
#pragma unroll
    for (int c = 0; c < 8; c++) {
        float* f = (float*)&v[c];
#pragma unroll
        for (int j = 0; j < 4; j++) {
            f[j] = expf(f[j] - m);
            s += f[j];
        }
    }
#pragma unroll
    for (int o = 32; o > 0; o >>= 1) s += __shfl_down(s, o, 64);
    if ((tid & 63) == 0) red[tid >> 6] = s;
    __syncthreads();
    float tot = 0.f;
#pragma unroll
    for (int w = 0; w < 16; w++) tot += red[w];
    const float inv = 1.0f / tot;

#pragma unroll
    for (int c = 0; c < 7; c++) {
        float4 o4;
        o4.x = v[c].x * inv; o4.y = v[c].y * inv;
        o4.z = v[c].z * inv; o4.w = v[c].w * inv;
        *(float4*)&r[(c << 12) + base] = o4;
    }
    if (tail) {
        float4 o4;
        o4.x = v[7].x * inv; o4.y = v[7].y * inv;
        o4.z = v[7].z * inv; o4.w = v[7].w * inv;
        *(float4*)&r[28672 + base] = o4;
    }
}

extern "C" void kernel_launch(void* const* d_in, const int* in_sizes, int n_in,
                              void* d_out, int out_size, void* d_ws, size_t ws_size,
                              hipStream_t stream)
{
    const float* x   = (const float*)d_in[0];
    const float* Wq  = (const float*)d_in[1];
    const float* bq  = (const float*)d_in[2];
    const float* Wk  = (const float*)d_in[3];
    const float* bk  = (const float*)d_in[4];
    const float* Wv  = (const float*)d_in[5];
    const float* bv  = (const float*)d_in[6];
    const float* Wp  = (const float*)d_in[7];
    const float* bp  = (const float*)d_in[8];
    const float* g1  = (const float*)d_in[9];
    const float* be1 = (const float*)d_in[10];
    const float* W1  = (const float*)d_in[11];
    const float* b1  = (const float*)d_in[12];
    const float* W2  = (const float*)d_in[13];
    const float* b2  = (const float*)d_in[14];
    const float* g2  = (const float*)d_in[15];
    const float* be2 = (const float*)d_in[16];
    const float* Wf  = (const float*)d_in[17];
    const float* bf  = (const float*)d_in[18];
    float* out = (float*)d_out;

    // ---- workspace carve (aligned 256B) ----
    char* ws = (char*)d_ws;
    auto alloc = [&](size_t bytes) {
        void* p = ws;
        ws += (bytes + 255) & ~(size_t)255;
        return p;
    };
    float*    x0     = (float*)alloc((size_t)SEQ * DIM * 4);
    float*    x1     = (float*)alloc((size_t)SEQ * DIM * 4);
    float*    z2p    = (float*)alloc((size_t)4 * SEQ * DIM * 4);           // splitk partials
    float*    sc     = (float*)alloc((size_t)2 * SEQ * SEQ * 4);           // score partials
    float*    PtA    = (float*)alloc((size_t)NLAYER * FDIM * DIM * 4);     // (W1@W2)^T
    float*    WvpA   = (float*)alloc((size_t)NLAYER * FDIM * DIM * 4);     // (Wv@Wp)^T
    ushort_t* QKh    = (ushort_t*)alloc((size_t)SEQ * 1024 * 2);
    ushort_t* QKl    = (ushort_t*)alloc((size_t)SEQ * 1024 * 2);
    ushort_t* X0h    = (ushort_t*)alloc((size_t)SEQ * DIM * 2);
    ushort_t* X0l    = (ushort_t*)alloc((size_t)SEQ * DIM * 2);
    ushort_t* X1h    = (ushort_t*)alloc((size_t)SEQ * DIM * 2);
    ushort_t* X1l    = (ushort_t*)alloc((size_t)SEQ * DIM * 2);
    ushort_t* AttH   = (ushort_t*)alloc((size_t)SEQ * SEQ * 2);
    ushort_t* AttL   = (ushort_t*)alloc((size_t)SEQ * SEQ * 2);
    ushort_t* Wbh    = (ushort_t*)alloc((size_t)NLAYER * 1536 * 512 * 2);  // [Wq;Wk;Wvp]^T
    ushort_t* Wbl    = (ushort_t*)alloc((size_t)NLAYER * 1536 * 512 * 2);
    ushort_t* WpTh   = (ushort_t*)alloc((size_t)NLAYER * 512 * 512 * 2);
    ushort_t* WpTl   = (ushort_t*)alloc((size_t)NLAYER * 512 * 512 * 2);
    ushort_t* Wvh    = (ushort_t*)alloc((size_t)NLAYER * 512 * 512 * 2);
    ushort_t* Wvl    = (ushort_t*)alloc((size_t)NLAYER * 512 * 512 * 2);
    ushort_t* W2th   = (ushort_t*)alloc((size_t)NLAYER * 512 * 2048 * 2);
    ushort_t* W2tl   = (ushort_t*)alloc((size_t)NLAYER * 512 * 2048 * 2);
    ushort_t* W1h    = (ushort_t*)alloc((size_t)NLAYER * 512 * 2048 * 2);
    ushort_t* W1l    = (ushort_t*)alloc((size_t)NLAYER * 512 * 2048 * 2);
    ushort_t* Pth    = (ushort_t*)alloc((size_t)NLAYER * 512 * 512 * 2);
    ushort_t* Ptl    = (ushort_t*)alloc((size_t)NLAYER * 512 * 512 * 2);
    ushort_t* VpTh   = (ushort_t*)alloc((size_t)FDIM * SEQ * 2);
    ushort_t* VpTl   = (ushort_t*)alloc((size_t)FDIM * SEQ * 2);
    ushort_t* Wfh    = (ushort_t*)alloc((size_t)VOCAB * DIM * 2);
    ushort_t* Wfl    = (ushort_t*)alloc((size_t)VOCAB * DIM * 2);
    float*    bqkvA  = (float*)alloc((size_t)NLAYER * 1536 * 4);
    float*    bvpA   = (float*)alloc((size_t)NLAYER * DIM * 4);
    float*    bvecA  = (float*)alloc((size_t)NLAYER * DIM * 4);

    const float att_scale = 1.0f / sqrtf((float)FDIM);
    const dim3 b256(256), b128(128), b1024(1024);

    // ================= weight prep (all layers, batched) =================
    hipMemcpyAsync(x0, x, (size_t)SEQ * DIM * 4, hipMemcpyDeviceToDevice, stream);
    // Wq^T, Wk^T -> Wb rows [0,512), [512,1024)
    tsplit_b_k<<<dim3(16, 16, NLAYER), b256, 0, stream>>>(Wq, FDIM, DIM, 262144, Wbh, Wbl, 786432);
    tsplit_b_k<<<dim3(16, 16, NLAYER), b256, 0, stream>>>(Wk, FDIM, DIM, 262144, Wbh + 262144, Wbl + 262144, 786432);
    // Wp^T, Wv (plain) for Wvp
    tsplit_b_k<<<dim3(16, 16, NLAYER), b256, 0, stream>>>(Wp, FDIM, FDIM, 262144, WpTh, WpTl, 262144);
    split_k<<<dim3(1, NLAYER * 512), b128, 0, stream>>>(Wv, 512, 512, Wvh, Wvl);
    // WvpT[l] = WpT[l] @ Wv[l]^T = (Wv@Wp)^T : batched, splitk=2 atomic
    hipMemsetAsync(WvpA, 0, (size_t)NLAYER * FDIM * DIM * 4, stream);
    gemm_bf16x3_k<<<dim3(4, 4, NLAYER * 2), b256, 0, stream>>>(
        WpTh, WpTl, Wvh, Wvl, nullptr, WvpA, 512, 512, 512, 512, 1.0f, 2, 0,
        262144, 262144, 262144, 0, 0);
    // Wb v-rows: B[1024+f][k] = Wvp[k][f] = WvpT[f][k] -> plain split into offset
    split_b_k<<<dim3(1, 512, NLAYER), b128, 0, stream>>>(
        WvpA, 512, 512, 262144, Wbh + 524288, Wbl + 524288, 786432);
    // bvp[l] = bv[l] @ Wp[l]
    hipMemsetAsync(bvpA, 0, (size_t)NLAYER * DIM * 4, stream);
    bvecg_k<<<dim3(4, 4, NLAYER), b256, 0, stream>>>(bv, Wp, bvpA, 512, 262144);
    // FFN collapse: W2^T, W1, Pt = (W1@W2)^T
    tsplit_b_k<<<dim3(16, 64, NLAYER), b256, 0, stream>>>(W2, DIM, HDIM, HDIM * DIM, W2th, W2tl, 1048576);
    split_k<<<dim3(4, NLAYER * 512), b128, 0, stream>>>(W1, HDIM, HDIM, W1h, W1l);
    hipMemsetAsync(PtA, 0, (size_t)NLAYER * FDIM * DIM * 4, stream);
    gemm_bf16x3_k<<<dim3(4, 4, NLAYER * 8), b256, 0, stream>>>(
        W2th, W2tl, W1h, W1l, nullptr, PtA, HDIM, HDIM, HDIM, DIM, 1.0f, 8, 0,
        1048576, 1048576, 262144, 0, 0);
    split_k<<<dim3(1, NLAYER * 512), b128, 0, stream>>>(PtA, DIM, DIM, Pth, Ptl);
    // biases
    hipMemcpyAsync(bvecA, b2, (size_t)NLAYER * DIM * 4, hipMemcpyDeviceToDevice, stream);
    bvecg_k<<<dim3(4, 16, NLAYER), b256, 0, stream>>>(b1, W2, bvecA, HDIM, HDIM * DIM);
    gatherqkv_k<<<dim3(24), b256, 0, stream>>>(bq, bk, bvpA, bqkvA);
    // Wf^T whole [32000][512]
    tsplit_k<<<dim3(VOCAB / 32, DIM / 32), b256, 0, stream>>>(Wf, VOCAB, DIM, Wfh, Wfl);
    // initial split of x
    split_k<<<dim3(1, SEQ), b128, 0, stream>>>(x0, DIM, DIM, X0h, X0l);

    // ================= layers (7 launches each, no memsets/atomics) =================
    for (int l = 0; l < NLAYER; l++) {
        // QKV+Vp fused: q,k -> QK [SEQ][1024]; vp -> VpT [512][SEQ] transposed
        gemm_qkv_k<<<dim3(12, 16), b256, 0, stream>>>(
            X0h, X0l, Wbh + (size_t)l * 786432, Wbl + (size_t)l * 786432,
            bqkvA + (size_t)l * 1536, QKh, QKl, VpTh, VpTl);

        // scores partials = scale * q @ k^T (causal block-skip, splitk=2)
        gemm_bf16x3_k<<<dim3(16, 16, 2), b256, 0, stream>>>(
            QKh, QKl, QKh + 512, QKl + 512, nullptr, sc,
            FDIM, 1024, 1024, SEQ, att_scale, 2, 1, 0, 0, 0, 0, SEQ * SEQ);

        // softmax over partial sum, fused bf16 split (clipped stores)
        softmax_causal_split_k<<<dim3(SEQ), b256, 0, stream>>>(sc, AttH, AttL);

        // z2 partials = att @ Vp + bp (causal K-clamp, splitk=4)
        gemm_bf16x3_k<<<dim3(4, 16, 4), b256, 0, stream>>>(
            AttH, AttL, VpTh, VpTl, bp + l * FDIM, z2p,
            SEQ, SEQ, SEQ, DIM, 1.0f, 4, 2, 0, 0, 0, 0, SEQ * DIM);

        // x1 = LN(sum(z2p) + x0), fused split; partial p valid iff p*512 <= row
        add_ln_split_k<<<dim3(SEQ), b256, 0, stream>>>(
            z2p, x0, g1 + l * FDIM, be1 + l * FDIM, x1, X1h, X1l, 4, 1);

        // h2 partials = x1 @ (W1@W2) + bvec (splitk=4)
        gemm_bf16x3_k<<<dim3(4, 16, 4), b256, 0, stream>>>(
            X1h, X1l, Pth + (size_t)l * 262144, Ptl + (size_t)l * 262144,
            bvecA + (size_t)l * DIM, z2p, DIM, DIM, DIM, DIM, 1.0f, 4, 0,
            0, 0, 0, 0, SEQ * DIM);

        // x0 = LN(sum(z2p) + x1), fused split
        add_ln_split_k<<<dim3(SEQ), b256, 0, stream>>>(
            z2p, x1, g2 + l * DIM, be2 + l * DIM, x0, X0h, X0l, 4, 0);
    }

    // logits = x0 @ Wf + bf: grid-swapped (flags=4) so the 16 M-tiles of each
    // Wf panel are consecutive -> panel fetched from HBM once.
    gemm_bf16x3_k<<<dim3(SEQ / 128, VOCAB / 128, 1), b256, 0, stream>>>(
        X0h, X0l, Wfh, Wfl, bf, out, DIM, DIM, DIM, VOCAB, 1.0f, 1, 4,
        0, 0, 0, 0, 0);
    softmax_rows_k<<<dim3(SEQ), b1024, 0, stream>>>(out);
}